// Round 7
// baseline (2951.041 us; speedup 1.0000x reference)
//
#include <hip/hip_runtime.h>

#define NFEAT 20
#define EFEAT 20
#define HID   64
#define NENV  16
#define NNODES 5000
#define NEDGES 50000
#define E2 (2*NEDGES)          // 100000 directed edges
#define ITERS 3
#define ROWS 128               // edge rows per block (2 waves x 64 rows)
#define NPAD 24                // padded per-node split row (20 + 4 junk)

typedef __attribute__((ext_vector_type(8))) short bf16x8;
typedef __attribute__((ext_vector_type(4))) float f32x4;

__device__ __forceinline__ ushort f2b(float f) {   // f32 -> bf16 RNE (prep only)
    unsigned u = __float_as_uint(f);
    u = (u + 0x7fffu + ((u >> 16) & 1u)) >> 16;
    return (ushort)u;
}
__device__ __forceinline__ float b2f(ushort h) {
    return __uint_as_float(((unsigned)h) << 16);
}
// tanh = 1 - 2/(exp(2x)+1); exact limits at +-inf, no clamps needed. 5 VALU ops.
__device__ __forceinline__ float fast_tanh(float x) {
    float e = __builtin_exp2f(x * 2.8853900817779268f);   // exp(2x)
    float r = __builtin_amdgcn_rcpf(e + 1.f);
    return fmaf(-2.f, r, 1.f);
}
__device__ __forceinline__ float fast_sigmoid(float x) {
    float e = __builtin_exp2f(x * -1.4426950408889634f);  // exp(-x)
    return __builtin_amdgcn_rcpf(1.f + e);
}

// Weights -> split-bf16 (RNE hi + RNE residual), layout [out][k], K padded to 64.
// W1 K-layout matches padded X rows: k<20 = src feats, 24<=k<44 = dst feats, else 0.
__global__ void prep_weights(const float* __restrict__ W1, const float* __restrict__ W2,
                             const float* __restrict__ W3,
                             ushort* __restrict__ W1h, ushort* __restrict__ W1l,
                             ushort* __restrict__ W2h, ushort* __restrict__ W2l,
                             ushort* __restrict__ W3h, ushort* __restrict__ W3l) {
    int t = threadIdx.x;
    for (int i = t; i < 64 * 64; i += 256) {
        int n = i >> 6, k = i & 63;
        float v = 0.f;
        if (k < NFEAT)                 v = W1[n * (2 * NFEAT) + k];
        else if (k >= NPAD && k < NPAD + NFEAT) v = W1[n * (2 * NFEAT) + NFEAT + (k - NPAD)];
        ushort h = f2b(v);
        W1h[i] = h; W1l[i] = f2b(v - b2f(h));
    }
    for (int i = t; i < 64 * 64; i += 256) {
        float v = W2[i];
        ushort h = f2b(v);
        W2h[i] = h; W2l[i] = f2b(v - b2f(h));
    }
    for (int i = t; i < 32 * 64; i += 256) {
        int n = i >> 6, k = i & 63;
        float v = (n < EFEAT) ? W3[n * HID + k] : 0.f;
        ushort h = f2b(v);
        W3h[i] = h; W3l[i] = f2b(v - b2f(h));
    }
}

// Initial per-node split (iteration 0); iterations 1,2 get splits from gru_kernel.
__global__ __launch_bounds__(256) void split_nf(const float* __restrict__ nf,
                                                ushort* __restrict__ nfh,
                                                ushort* __restrict__ nfl) {
    int gid = blockIdx.x * 256 + threadIdx.x;
    if (gid >= NENV * NNODES) return;
    const float* p = nf + (size_t)gid * NFEAT;
    ushort* ph = nfh + (size_t)gid * NPAD;
    ushort* pl = nfl + (size_t)gid * NPAD;
    #pragma unroll
    for (int k = 0; k < NFEAT; k++) {
        float v = p[k];
        unsigned u = __float_as_uint(v);
        ph[k] = (ushort)(u >> 16);                      // truncated hi
        float lo = v - __uint_as_float(u & 0xffff0000u);
        pl[k] = (ushort)(__float_as_uint(lo) >> 16);    // truncated lo (~2^-17 repr err)
    }
    *(uint2*)(ph + NFEAT) = make_uint2(0u, 0u);         // zero pad cols 20..23
    *(uint2*)(pl + NFEAT) = make_uint2(0u, 0u);
}

// tanh + truncation-split 4 consecutive cols of one row -> one b64 write per plane.
__device__ __forceinline__ void store_acts(ushort* __restrict__ baseh,
                                           ushort* __restrict__ basel,
                                           int rr, int c0, f32x4 acc) {
    float t0 = fast_tanh(acc[0]), t1 = fast_tanh(acc[1]);
    float t2 = fast_tanh(acc[2]), t3 = fast_tanh(acc[3]);
    unsigned u0 = __float_as_uint(t0), u1 = __float_as_uint(t1);
    unsigned u2 = __float_as_uint(t2), u3 = __float_as_uint(t3);
    unsigned h01 = __builtin_amdgcn_perm(u1, u0, 0x07060302u);  // [hi16(t0),hi16(t1)]
    unsigned h23 = __builtin_amdgcn_perm(u3, u2, 0x07060302u);
    float l0 = t0 - __uint_as_float(u0 & 0xffff0000u);
    float l1 = t1 - __uint_as_float(u1 & 0xffff0000u);
    float l2 = t2 - __uint_as_float(u2 & 0xffff0000u);
    float l3 = t3 - __uint_as_float(u3 & 0xffff0000u);
    unsigned lo01 = __builtin_amdgcn_perm(__float_as_uint(l1), __float_as_uint(l0), 0x07060302u);
    unsigned lo23 = __builtin_amdgcn_perm(__float_as_uint(l3), __float_as_uint(l2), 0x07060302u);
    int g = c0 >> 3;
    int idx = rr * 64 + ((g ^ (rr & 7)) << 3) + (c0 & 7);       // ushort units, 8B aligned
    *(uint2*)(baseh + idx) = make_uint2(h01, h23);
    *(uint2*)(basel + idx) = make_uint2(lo01, lo23);
}

// 128 edge-rows/block, 2 waves, wave-local (no barriers). Operand-swapped MFMA:
// A = W[out][k] (global, L1-hot), B = X^T (LDS, b128 per fragment by symmetry).
// D[out][xrow]: lane owns 4 consecutive outs of one row -> b64 epilogue writes.
// Split-bf16 compensated: acc = Wh*Xh + Wl*Xh + Wh*Xl per K-tile.
__global__ __launch_bounds__(ROWS) void edge_mlp_mfma(
    const ushort* __restrict__ nfh, const ushort* __restrict__ nfl,  // (ENV,NODE,24) split planes
    const int*   __restrict__ edges,
    const ushort* __restrict__ W1h, const ushort* __restrict__ W1l,
    const ushort* __restrict__ W2h, const ushort* __restrict__ W2l,
    const ushort* __restrict__ W3h, const ushort* __restrict__ W3l,
    const float* __restrict__ b1, const float* __restrict__ b2,
    const float* __restrict__ b3,
    float* __restrict__ store)
{
    __shared__ bf16x8 Ahi[ROWS * 8], Alo[ROWS * 8];   // 16 KB each: X -> H1 -> H2 in place
    ushort* Ahi16 = (ushort*)Ahi; ushort* Alo16 = (ushort*)Alo;

    const int tid = threadIdx.x;

    // ---- gather: pre-split node rows, pure loads+stores (no VALU packing) ----
    {
        int gid = blockIdx.x * ROWS + tid;
        int env = gid / E2;
        int e   = gid - env * E2;
        int src = edges[e];
        int dst = (e < NEDGES) ? edges[NEDGES + e] : edges[e - NEDGES];
        const bf16x8* sh = (const bf16x8*)(nfh + ((size_t)env * NNODES + src) * NPAD);
        const bf16x8* sl = (const bf16x8*)(nfl + ((size_t)env * NNODES + src) * NPAD);
        const bf16x8* dh = (const bf16x8*)(nfh + ((size_t)env * NNODES + dst) * NPAD);
        const bf16x8* dl = (const bf16x8*)(nfl + ((size_t)env * NNODES + dst) * NPAD);
        int rb = tid * 8, sw = tid & 7;
        bf16x8 z = {0,0,0,0,0,0,0,0};
        Ahi[rb + (0 ^ sw)] = sh[0]; Alo[rb + (0 ^ sw)] = sl[0];
        Ahi[rb + (1 ^ sw)] = sh[1]; Alo[rb + (1 ^ sw)] = sl[1];
        Ahi[rb + (2 ^ sw)] = sh[2]; Alo[rb + (2 ^ sw)] = sl[2];
        Ahi[rb + (3 ^ sw)] = dh[0]; Alo[rb + (3 ^ sw)] = dl[0];
        Ahi[rb + (4 ^ sw)] = dh[1]; Alo[rb + (4 ^ sw)] = dl[1];
        Ahi[rb + (5 ^ sw)] = dh[2]; Alo[rb + (5 ^ sw)] = dl[2];
        Ahi[rb + (6 ^ sw)] = z;     Alo[rb + (6 ^ sw)] = z;
        Ahi[rb + (7 ^ sw)] = z;     Alo[rb + (7 ^ sw)] = z;
    }

    const int wave = tid >> 6;
    const int lane = tid & 63;
    const int lr   = lane & 15;      // B-col = x-row-in-tile / A-row = out-dim for frags
    const int kg   = lane >> 4;      // k-group; C rows = out = kg*4+r
    const int m0   = wave * 64;

#define MFMA6(acc, wh0, wl0, wh1, wl1, xh0, xl0, xh1, xl1)                          \
    acc = __builtin_amdgcn_mfma_f32_16x16x32_bf16(wh0, xh0, acc, 0, 0, 0);          \
    acc = __builtin_amdgcn_mfma_f32_16x16x32_bf16(wl0, xh0, acc, 0, 0, 0);          \
    acc = __builtin_amdgcn_mfma_f32_16x16x32_bf16(wh0, xl0, acc, 0, 0, 0);          \
    acc = __builtin_amdgcn_mfma_f32_16x16x32_bf16(wh1, xh1, acc, 0, 0, 0);          \
    acc = __builtin_amdgcn_mfma_f32_16x16x32_bf16(wl1, xh1, acc, 0, 0, 0);          \
    acc = __builtin_amdgcn_mfma_f32_16x16x32_bf16(wh1, xl1, acc, 0, 0, 0);

#define GEMM_LAYER(Wh, Wl, bias)                                                    \
    {                                                                               \
        bf16x8 wh[4][2], wl[4][2];                                                  \
        f32x4 binit[4];                                                             \
        _Pragma("unroll")                                                           \
        for (int n = 0; n < 4; n++) {                                               \
            _Pragma("unroll")                                                       \
            for (int kt = 0; kt < 2; kt++) {                                        \
                wh[n][kt] = *(const bf16x8*)(Wh + (n * 16 + lr) * 64 + kt * 32 + kg * 8); \
                wl[n][kt] = *(const bf16x8*)(Wl + (n * 16 + lr) * 64 + kt * 32 + kg * 8); \
            }                                                                       \
            binit[n] = *(const f32x4*)(bias + n * 16 + kg * 4);                     \
        }                                                                           \
        for (int m = 0; m < 4; m++) {                                               \
            int rr = m0 + m * 16 + lr, sw = rr & 7;                                 \
            bf16x8 xh0 = Ahi[rr * 8 + (kg ^ sw)];                                   \
            bf16x8 xl0 = Alo[rr * 8 + (kg ^ sw)];                                   \
            bf16x8 xh1 = Ahi[rr * 8 + ((4 + kg) ^ sw)];                             \
            bf16x8 xl1 = Alo[rr * 8 + ((4 + kg) ^ sw)];                             \
            f32x4 acc[4];                                                           \
            _Pragma("unroll")                                                       \
            for (int n = 0; n < 4; n++) {                                           \
                acc[n] = binit[n];                                                  \
                MFMA6(acc[n], wh[n][0], wl[n][0], wh[n][1], wl[n][1], xh0, xl0, xh1, xl1) \
            }                                                                       \
            _Pragma("unroll")                                                       \
            for (int n = 0; n < 4; n++)                                             \
                store_acts(Ahi16, Alo16, rr, n * 16 + kg * 4, acc[n]);              \
        }                                                                           \
    }

    GEMM_LAYER(W1h, W1l, b1)   // X -> H1 (in place)
    GEMM_LAYER(W2h, W2l, b2)   // H1 -> H2 (in place)

    // ---- GEMM3: H2 @ W3^T + b3 -> atomic scatter; one src calc per row ----
    {
        bf16x8 wh[2][2], wl[2][2];
        #pragma unroll
        for (int n = 0; n < 2; n++)
            #pragma unroll
            for (int kt = 0; kt < 2; kt++) {
                wh[n][kt] = *(const bf16x8*)(W3h + (n * 16 + lr) * 64 + kt * 32 + kg * 8);
                wl[n][kt] = *(const bf16x8*)(W3l + (n * 16 + lr) * 64 + kt * 32 + kg * 8);
            }
        f32x4 binit0 = *(const f32x4*)(b3 + kg * 4);
        f32x4 binit1 = (kg == 0) ? *(const f32x4*)(b3 + 16) : f32x4{0.f,0.f,0.f,0.f};
        for (int m = 0; m < 4; m++) {
            int rr = m0 + m * 16 + lr, sw = rr & 7;
            bf16x8 xh0 = Ahi[rr * 8 + (kg ^ sw)];
            bf16x8 xl0 = Alo[rr * 8 + (kg ^ sw)];
            bf16x8 xh1 = Ahi[rr * 8 + ((4 + kg) ^ sw)];
            bf16x8 xl1 = Alo[rr * 8 + ((4 + kg) ^ sw)];
            f32x4 acc0 = binit0, acc1 = binit1;
            MFMA6(acc0, wh[0][0], wl[0][0], wh[0][1], wl[0][1], xh0, xl0, xh1, xl1)
            MFMA6(acc1, wh[1][0], wl[1][0], wh[1][1], wl[1][1], xh0, xl0, xh1, xl1)
            int gid = blockIdx.x * ROWS + rr;
            int env = gid / E2;
            int e   = gid - env * E2;
            int src = edges[e];                 // src of BOTH edge directions
            float* sp = store + ((size_t)env * NNODES + src) * EFEAT + kg * 4;
            #pragma unroll
            for (int r = 0; r < 4; r++) atomicAdd(sp + r, acc0[r]);
            if (kg == 0) {
                #pragma unroll
                for (int r = 0; r < 4; r++) atomicAdd(sp + 16 + r, acc1[r]);
            }
        }
    }
#undef GEMM_LAYER
#undef MFMA6
}

// GRU single step per (env,node); emits f32 nf AND the split planes for the
// next iteration's edge gather (dedupes the split 20x vs per-edge).
__global__ __launch_bounds__(256) void gru_kernel(
    const float* __restrict__ store,
    const float* __restrict__ Wih, const float* __restrict__ bih,
    const float* __restrict__ Whh, const float* __restrict__ bhh,
    float* __restrict__ nf,
    ushort* __restrict__ nfh, ushort* __restrict__ nfl)
{
    int gid = blockIdx.x * blockDim.x + threadIdx.x;
    const int total = NENV * NNODES;
    if (gid >= total) return;

    const float* s = store + (size_t)gid * EFEAT;
    float*       h = nf    + (size_t)gid * NFEAT;
    ushort*     ph = nfh   + (size_t)gid * NPAD;
    ushort*     pl = nfl   + (size_t)gid * NPAD;

    float sv[EFEAT], hv[NFEAT];
    #pragma unroll
    for (int k = 0; k < EFEAT; k++) sv[k] = s[k];
    #pragma unroll
    for (int k = 0; k < NFEAT; k++) hv[k] = h[k];

    for (int t = 0; t < NFEAT; t++) {
        float ir = bih[t],            hr = bhh[t];
        float iz = bih[NFEAT + t],    hz = bhh[NFEAT + t];
        float in_ = bih[2*NFEAT + t], hn = bhh[2*NFEAT + t];
        const float* wr = Wih + t * EFEAT;
        const float* wz = Wih + (NFEAT + t) * EFEAT;
        const float* wn = Wih + (2*NFEAT + t) * EFEAT;
        #pragma unroll
        for (int k = 0; k < EFEAT; k++) {
            ir  = fmaf(sv[k], wr[k], ir);
            iz  = fmaf(sv[k], wz[k], iz);
            in_ = fmaf(sv[k], wn[k], in_);
        }
        const float* vr = Whh + t * NFEAT;
        const float* vz = Whh + (NFEAT + t) * NFEAT;
        const float* vn = Whh + (2*NFEAT + t) * NFEAT;
        #pragma unroll
        for (int k = 0; k < NFEAT; k++) {
            hr = fmaf(hv[k], vr[k], hr);
            hz = fmaf(hv[k], vz[k], hz);
            hn = fmaf(hv[k], vn[k], hn);
        }
        float r = fast_sigmoid(ir + hr);
        float z = fast_sigmoid(iz + hz);
        float n = fast_tanh(in_ + r * hn);
        float hw = (1.f - z) * n + z * hv[t];
        h[t] = hw;
        unsigned u = __float_as_uint(hw);
        ph[t] = (ushort)(u >> 16);
        float lo = hw - __uint_as_float(u & 0xffff0000u);
        pl[t] = (ushort)(__float_as_uint(lo) >> 16);
    }
    *(uint2*)(ph + NFEAT) = make_uint2(0u, 0u);
    *(uint2*)(pl + NFEAT) = make_uint2(0u, 0u);
}

extern "C" void kernel_launch(void* const* d_in, const int* in_sizes, int n_in,
                              void* d_out, int out_size, void* d_ws, size_t ws_size,
                              hipStream_t stream) {
    const float* nf_in = (const float*)d_in[0];
    const int*   edges = (const int*)d_in[1];
    const float* W1 = (const float*)d_in[2];
    const float* b1 = (const float*)d_in[3];
    const float* W2 = (const float*)d_in[4];
    const float* b2 = (const float*)d_in[5];
    const float* W3 = (const float*)d_in[6];
    const float* b3 = (const float*)d_in[7];
    const float* Wih = (const float*)d_in[8];
    const float* Whh = (const float*)d_in[9];
    const float* bih = (const float*)d_in[10];
    const float* bhh = (const float*)d_in[11];

    float* nf    = (float*)d_out;
    float* store = (float*)d_ws;
    const size_t nf_bytes    = (size_t)NENV * NNODES * NFEAT * sizeof(float);
    const size_t store_bytes = (size_t)NENV * NNODES * EFEAT * sizeof(float);
    // ws layout: store | W splits (40 KB) | nfh | nfl  (~14.1 MB total)
    ushort* W1h = (ushort*)((char*)d_ws + store_bytes);
    ushort* W1l = W1h + 64 * 64;
    ushort* W2h = W1l + 64 * 64;
    ushort* W2l = W2h + 64 * 64;
    ushort* W3h = W2l + 64 * 64;
    ushort* W3l = W3h + 32 * 64;
    ushort* nfh = W3l + 32 * 64;
    ushort* nfl = nfh + (size_t)NENV * NNODES * NPAD;

    prep_weights<<<1, 256, 0, stream>>>(W1, W2, W3, W1h, W1l, W2h, W2l, W3h, W3l);
    split_nf<<<(NENV * NNODES + 255) / 256, 256, 0, stream>>>(nf_in, nfh, nfl);
    hipMemcpyAsync(nf, nf_in, nf_bytes, hipMemcpyDeviceToDevice, stream);

    const int edge_blocks = (NENV * E2) / ROWS;           // 12500, exact
    dim3 grid_n((NENV * NNODES + 255) / 256);

    for (int it = 0; it < ITERS; it++) {
        hipMemsetAsync(store, 0, store_bytes, stream);
        edge_mlp_mfma<<<edge_blocks, ROWS, 0, stream>>>(nfh, nfl, edges,
                                                        W1h, W1l, W2h, W2l, W3h, W3l,
                                                        b1, b2, b3, store);
        gru_kernel<<<grid_n, 256, 0, stream>>>(store, Wih, bih, Whh, bhh, nf, nfh, nfl);
    }
}

// Round 8
// 1126.245 us; speedup vs baseline: 2.6202x; 2.6202x over previous
//
#include <hip/hip_runtime.h>

#define NFEAT 20
#define EFEAT 20
#define HID   64
#define NENV  16
#define NNODES 5000
#define NEDGES 50000
#define E2 (2*NEDGES)          // 100000 directed edges
#define ITERS 3
#define ROWS 128               // edge rows per block
#define THREADS 256            // 4 waves; wave w owns rows [w*32, w*32+32)
#define NPAD 24                // padded per-node split row (20 + 4 junk)

typedef __attribute__((ext_vector_type(8))) short bf16x8;
typedef __attribute__((ext_vector_type(4))) float f32x4;

__device__ __forceinline__ ushort f2b(float f) {   // f32 -> bf16 RNE (prep only)
    unsigned u = __float_as_uint(f);
    u = (u + 0x7fffu + ((u >> 16) & 1u)) >> 16;
    return (ushort)u;
}
__device__ __forceinline__ float b2f(ushort h) {
    return __uint_as_float(((unsigned)h) << 16);
}
// tanh = 1 - 2/(exp(2x)+1); exact limits at +-inf, no clamps. ~5 VALU ops.
__device__ __forceinline__ float fast_tanh(float x) {
    float e = __builtin_exp2f(x * 2.8853900817779268f);   // exp(2x)
    float r = __builtin_amdgcn_rcpf(e + 1.f);
    return fmaf(-2.f, r, 1.f);
}
__device__ __forceinline__ float fast_sigmoid(float x) {
    float e = __builtin_exp2f(x * -1.4426950408889634f);  // exp(-x)
    return __builtin_amdgcn_rcpf(1.f + e);
}

// Weights -> split-bf16 (RNE hi + RNE residual), layout [out][k], K padded to 64.
// W1 K-layout matches padded X rows: k<20 = src feats, 24<=k<44 = dst feats, else 0.
__global__ void prep_weights(const float* __restrict__ W1, const float* __restrict__ W2,
                             const float* __restrict__ W3,
                             ushort* __restrict__ W1h, ushort* __restrict__ W1l,
                             ushort* __restrict__ W2h, ushort* __restrict__ W2l,
                             ushort* __restrict__ W3h, ushort* __restrict__ W3l) {
    int t = threadIdx.x;
    for (int i = t; i < 64 * 64; i += 256) {
        int n = i >> 6, k = i & 63;
        float v = 0.f;
        if (k < NFEAT)                          v = W1[n * (2 * NFEAT) + k];
        else if (k >= NPAD && k < NPAD + NFEAT) v = W1[n * (2 * NFEAT) + NFEAT + (k - NPAD)];
        ushort h = f2b(v);
        W1h[i] = h; W1l[i] = f2b(v - b2f(h));
    }
    for (int i = t; i < 64 * 64; i += 256) {
        float v = W2[i];
        ushort h = f2b(v);
        W2h[i] = h; W2l[i] = f2b(v - b2f(h));
    }
    for (int i = t; i < 32 * 64; i += 256) {
        int n = i >> 6, k = i & 63;
        float v = (n < EFEAT) ? W3[n * HID + k] : 0.f;
        ushort h = f2b(v);
        W3h[i] = h; W3l[i] = f2b(v - b2f(h));
    }
}

// Initial per-node truncation split (iteration 0); later iters come from gru_kernel.
__global__ __launch_bounds__(256) void split_nf(const float* __restrict__ nf,
                                                ushort* __restrict__ nfh,
                                                ushort* __restrict__ nfl) {
    int gid = blockIdx.x * 256 + threadIdx.x;
    if (gid >= NENV * NNODES) return;
    const float* p = nf + (size_t)gid * NFEAT;
    ushort* ph = nfh + (size_t)gid * NPAD;
    ushort* pl = nfl + (size_t)gid * NPAD;
    #pragma unroll
    for (int k = 0; k < NFEAT; k++) {
        float v = p[k];
        unsigned u = __float_as_uint(v);
        ph[k] = (ushort)(u >> 16);                      // truncated hi
        float lo = v - __uint_as_float(u & 0xffff0000u);
        pl[k] = (ushort)(__float_as_uint(lo) >> 16);    // truncated lo (~2^-17 repr err)
    }
    *(uint2*)(ph + NFEAT) = make_uint2(0u, 0u);         // zero pad cols 20..23
    *(uint2*)(pl + NFEAT) = make_uint2(0u, 0u);
}

// 128 edge-rows/block, 4 waves, wave w owns rows [w*32,w*32+32) — gather writes
// and compute reads are wave-local => NO barriers. Round-6 validated orientation:
// A = X (LDS, swizzled), B = W (global, L1-hot), C[row=edge][col=out].
// Split-bf16 compensated: acc = Xh*Wh + Xl*Wh + Xh*Wl per K-tile. Bias in acc-init.
__global__ __launch_bounds__(THREADS) void edge_mlp_mfma(
    const ushort* __restrict__ nfh, const ushort* __restrict__ nfl,
    const int*   __restrict__ edges,
    const ushort* __restrict__ W1h, const ushort* __restrict__ W1l,
    const ushort* __restrict__ W2h, const ushort* __restrict__ W2l,
    const ushort* __restrict__ W3h, const ushort* __restrict__ W3l,
    const float* __restrict__ b1, const float* __restrict__ b2,
    const float* __restrict__ b3,
    float* __restrict__ store)
{
    __shared__ bf16x8 Ahi[ROWS * 8], Alo[ROWS * 8];   // 16 KB each: X->H1->H2 in place
    ushort* Ahi16 = (ushort*)Ahi; ushort* Alo16 = (ushort*)Alo;

    const int tid = threadIdx.x;

    // ---- gather: 2 threads per edge row (src half / dst half), pure copy ----
    {
        int row  = tid >> 1, half = tid & 1;
        int grow = blockIdx.x * ROWS + row;
        int env  = grow / E2;
        int e    = grow - env * E2;
        int node;
        if (half == 0) node = edges[e];                               // src
        else           node = (e < NEDGES) ? edges[NEDGES + e] : edges[e - NEDGES];  // dst
        const bf16x8* nh = (const bf16x8*)(nfh + ((size_t)env * NNODES + node) * NPAD);
        const bf16x8* nl = (const bf16x8*)(nfl + ((size_t)env * NNODES + node) * NPAD);
        int rb = row * 8, sw = row & 7, g0 = half * 3;
        Ahi[rb + ((g0 + 0) ^ sw)] = nh[0]; Alo[rb + ((g0 + 0) ^ sw)] = nl[0];
        Ahi[rb + ((g0 + 1) ^ sw)] = nh[1]; Alo[rb + ((g0 + 1) ^ sw)] = nl[1];
        Ahi[rb + ((g0 + 2) ^ sw)] = nh[2]; Alo[rb + ((g0 + 2) ^ sw)] = nl[2];
        if (half) {
            bf16x8 z = {0,0,0,0,0,0,0,0};
            Ahi[rb + (6 ^ sw)] = z; Alo[rb + (6 ^ sw)] = z;
            Ahi[rb + (7 ^ sw)] = z; Alo[rb + (7 ^ sw)] = z;
        }
    }

    const int wave = tid >> 6;
    const int lane = tid & 63;
    const int lr   = lane & 15;      // A-row-in-tile / B-col / C-col
    const int kg   = lane >> 4;      // k-group for A/B; C row-group
    const int m0   = wave * 32;

#define MFMA6(acc, a0h, a0l, a1h, a1l, bh0, bl0, bh1, bl1)                          \
    acc = __builtin_amdgcn_mfma_f32_16x16x32_bf16(a0h, bh0, acc, 0, 0, 0);          \
    acc = __builtin_amdgcn_mfma_f32_16x16x32_bf16(a0l, bh0, acc, 0, 0, 0);          \
    acc = __builtin_amdgcn_mfma_f32_16x16x32_bf16(a0h, bl0, acc, 0, 0, 0);          \
    acc = __builtin_amdgcn_mfma_f32_16x16x32_bf16(a1h, bh1, acc, 0, 0, 0);          \
    acc = __builtin_amdgcn_mfma_f32_16x16x32_bf16(a1l, bh1, acc, 0, 0, 0);          \
    acc = __builtin_amdgcn_mfma_f32_16x16x32_bf16(a1h, bl1, acc, 0, 0, 0);

#define GEMM_LAYER(Wh, Wl, bias)                                                    \
    {                                                                               \
        bf16x8 wh[4][2], wl[4][2];                                                  \
        float bb[4];                                                                \
        _Pragma("unroll")                                                           \
        for (int n = 0; n < 4; n++) {                                               \
            _Pragma("unroll")                                                       \
            for (int kt = 0; kt < 2; kt++) {                                        \
                wh[n][kt] = *(const bf16x8*)(Wh + (n * 16 + lr) * 64 + kt * 32 + kg * 8); \
                wl[n][kt] = *(const bf16x8*)(Wl + (n * 16 + lr) * 64 + kt * 32 + kg * 8); \
            }                                                                       \
            bb[n] = bias[n * 16 + lr];                                              \
        }                                                                           \
        _Pragma("unroll")                                                           \
        for (int m = 0; m < 2; m++) {                                               \
            int arow = m0 + m * 16 + lr, sw = arow & 7;                             \
            bf16x8 a0h = Ahi[arow * 8 + (kg ^ sw)];                                 \
            bf16x8 a0l = Alo[arow * 8 + (kg ^ sw)];                                 \
            bf16x8 a1h = Ahi[arow * 8 + ((4 + kg) ^ sw)];                           \
            bf16x8 a1l = Alo[arow * 8 + ((4 + kg) ^ sw)];                           \
            f32x4 acc[4];                                                           \
            _Pragma("unroll")                                                       \
            for (int n = 0; n < 4; n++) {                                           \
                acc[n] = f32x4{bb[n], bb[n], bb[n], bb[n]};                         \
                MFMA6(acc[n], a0h, a0l, a1h, a1l, wh[n][0], wl[n][0], wh[n][1], wl[n][1]) \
            }                                                                       \
            _Pragma("unroll")                                                       \
            for (int n = 0; n < 4; n++) {                                           \
                int col = n * 16 + lr;                                              \
                _Pragma("unroll")                                                   \
                for (int r = 0; r < 4; r++) {                                       \
                    int row = m0 + m * 16 + kg * 4 + r;                             \
                    float t = fast_tanh(acc[n][r]);                                 \
                    unsigned u = __float_as_uint(t);                                \
                    int idx = row * 64 + (col ^ ((row & 7) << 3));                  \
                    Ahi16[idx] = (ushort)(u >> 16);                                 \
                    float lo = t - __uint_as_float(u & 0xffff0000u);                \
                    Alo16[idx] = (ushort)(__float_as_uint(lo) >> 16);               \
                }                                                                   \
            }                                                                       \
        }                                                                           \
    }

    GEMM_LAYER(W1h, W1l, b1)   // X  -> H1 (in place)
    GEMM_LAYER(W2h, W2l, b2)   // H1 -> H2 (in place)

    // ---- GEMM3: H2 @ W3^T + b3 -> atomic scatter to store[env][src] ----
    {
        bf16x8 wh[2][2], wl[2][2];
        #pragma unroll
        for (int n = 0; n < 2; n++)
            #pragma unroll
            for (int kt = 0; kt < 2; kt++) {
                wh[n][kt] = *(const bf16x8*)(W3h + (n * 16 + lr) * 64 + kt * 32 + kg * 8);
                wl[n][kt] = *(const bf16x8*)(W3l + (n * 16 + lr) * 64 + kt * 32 + kg * 8);
            }
        float bb0 = b3[lr];
        float bb1 = (lr < 4) ? b3[16 + lr] : 0.f;
        #pragma unroll
        for (int m = 0; m < 2; m++) {
            int arow = m0 + m * 16 + lr, sw = arow & 7;
            bf16x8 a0h = Ahi[arow * 8 + (kg ^ sw)];
            bf16x8 a0l = Alo[arow * 8 + (kg ^ sw)];
            bf16x8 a1h = Ahi[arow * 8 + ((4 + kg) ^ sw)];
            bf16x8 a1l = Alo[arow * 8 + ((4 + kg) ^ sw)];
            f32x4 acc0 = {bb0, bb0, bb0, bb0};
            f32x4 acc1 = {bb1, bb1, bb1, bb1};
            MFMA6(acc0, a0h, a0l, a1h, a1l, wh[0][0], wl[0][0], wh[0][1], wl[0][1])
            MFMA6(acc1, a0h, a0l, a1h, a1l, wh[1][0], wl[1][0], wh[1][1], wl[1][1])
            #pragma unroll
            for (int r = 0; r < 4; r++) {
                int row  = m0 + m * 16 + kg * 4 + r;
                int grow = blockIdx.x * ROWS + row;
                int env  = grow / E2;
                int e    = grow - env * E2;
                int src  = edges[e];               // src of BOTH edge directions
                float* sp = store + ((size_t)env * NNODES + src) * EFEAT;
                atomicAdd(sp + lr, acc0[r]);
                if (lr < 4) atomicAdd(sp + 16 + lr, acc1[r]);
            }
        }
    }
#undef GEMM_LAYER
#undef MFMA6
}

// GRU single step per (env,node); emits f32 nf AND next iteration's split planes.
__global__ __launch_bounds__(256) void gru_kernel(
    const float* __restrict__ store,
    const float* __restrict__ Wih, const float* __restrict__ bih,
    const float* __restrict__ Whh, const float* __restrict__ bhh,
    float* __restrict__ nf,
    ushort* __restrict__ nfh, ushort* __restrict__ nfl)
{
    int gid = blockIdx.x * blockDim.x + threadIdx.x;
    const int total = NENV * NNODES;
    if (gid >= total) return;

    const float* s = store + (size_t)gid * EFEAT;
    float*       h = nf    + (size_t)gid * NFEAT;
    ushort*     ph = nfh   + (size_t)gid * NPAD;
    ushort*     pl = nfl   + (size_t)gid * NPAD;

    float sv[EFEAT], hv[NFEAT];
    #pragma unroll
    for (int k = 0; k < EFEAT; k++) sv[k] = s[k];
    #pragma unroll
    for (int k = 0; k < NFEAT; k++) hv[k] = h[k];

    for (int t = 0; t < NFEAT; t++) {
        float ir = bih[t],            hr = bhh[t];
        float iz = bih[NFEAT + t],    hz = bhh[NFEAT + t];
        float in_ = bih[2*NFEAT + t], hn = bhh[2*NFEAT + t];
        const float* wr = Wih + t * EFEAT;
        const float* wz = Wih + (NFEAT + t) * EFEAT;
        const float* wn = Wih + (2*NFEAT + t) * EFEAT;
        #pragma unroll
        for (int k = 0; k < EFEAT; k++) {
            ir  = fmaf(sv[k], wr[k], ir);
            iz  = fmaf(sv[k], wz[k], iz);
            in_ = fmaf(sv[k], wn[k], in_);
        }
        const float* vr = Whh + t * NFEAT;
        const float* vz = Whh + (NFEAT + t) * NFEAT;
        const float* vn = Whh + (2*NFEAT + t) * NFEAT;
        #pragma unroll
        for (int k = 0; k < NFEAT; k++) {
            hr = fmaf(hv[k], vr[k], hr);
            hz = fmaf(hv[k], vz[k], hz);
            hn = fmaf(hv[k], vn[k], hn);
        }
        float r = fast_sigmoid(ir + hr);
        float z = fast_sigmoid(iz + hz);
        float n = fast_tanh(in_ + r * hn);
        float hw = (1.f - z) * n + z * hv[t];
        h[t] = hw;
        unsigned u = __float_as_uint(hw);
        ph[t] = (ushort)(u >> 16);
        float lo = hw - __uint_as_float(u & 0xffff0000u);
        pl[t] = (ushort)(__float_as_uint(lo) >> 16);
    }
    *(uint2*)(ph + NFEAT) = make_uint2(0u, 0u);
    *(uint2*)(pl + NFEAT) = make_uint2(0u, 0u);
}

extern "C" void kernel_launch(void* const* d_in, const int* in_sizes, int n_in,
                              void* d_out, int out_size, void* d_ws, size_t ws_size,
                              hipStream_t stream) {
    const float* nf_in = (const float*)d_in[0];
    const int*   edges = (const int*)d_in[1];
    const float* W1 = (const float*)d_in[2];
    const float* b1 = (const float*)d_in[3];
    const float* W2 = (const float*)d_in[4];
    const float* b2 = (const float*)d_in[5];
    const float* W3 = (const float*)d_in[6];
    const float* b3 = (const float*)d_in[7];
    const float* Wih = (const float*)d_in[8];
    const float* Whh = (const float*)d_in[9];
    const float* bih = (const float*)d_in[10];
    const float* bhh = (const float*)d_in[11];

    float* nf    = (float*)d_out;
    float* store = (float*)d_ws;
    const size_t nf_bytes    = (size_t)NENV * NNODES * NFEAT * sizeof(float);
    const size_t store_bytes = (size_t)NENV * NNODES * EFEAT * sizeof(float);
    // ws layout: store | W splits (40 KB) | nfh | nfl  (~14.1 MB total)
    ushort* W1h = (ushort*)((char*)d_ws + store_bytes);
    ushort* W1l = W1h + 64 * 64;
    ushort* W2h = W1l + 64 * 64;
    ushort* W2l = W2h + 64 * 64;
    ushort* W3h = W2l + 64 * 64;
    ushort* W3l = W3h + 32 * 64;
    ushort* nfh = W3l + 32 * 64;
    ushort* nfl = nfh + (size_t)NENV * NNODES * NPAD;

    prep_weights<<<1, 256, 0, stream>>>(W1, W2, W3, W1h, W1l, W2h, W2l, W3h, W3l);
    split_nf<<<(NENV * NNODES + 255) / 256, 256, 0, stream>>>(nf_in, nfh, nfl);
    hipMemcpyAsync(nf, nf_in, nf_bytes, hipMemcpyDeviceToDevice, stream);

    const int edge_blocks = (NENV * E2) / ROWS;           // 12500, exact
    dim3 grid_n((NENV * NNODES + 255) / 256);

    for (int it = 0; it < ITERS; it++) {
        hipMemsetAsync(store, 0, store_bytes, stream);
        edge_mlp_mfma<<<edge_blocks, THREADS, 0, stream>>>(nfh, nfl, edges,
                                                           W1h, W1l, W2h, W2l, W3h, W3l,
                                                           b1, b2, b3, store);
        gru_kernel<<<grid_n, 256, 0, stream>>>(store, Wih, bih, Whh, bhh, nf, nfh, nfl);
    }
}

// Round 10
// 1060.116 us; speedup vs baseline: 2.7837x; 1.0624x over previous
//
#include <hip/hip_runtime.h>

#define NFEAT 20
#define EFEAT 20
#define HID   64
#define NENV  16
#define NNODES 5000
#define NEDGES 50000
#define E2 (2*NEDGES)          // 100000 directed edges
#define ITERS 3
#define ROWS 128               // edge rows per block
#define THREADS 256            // 4 waves; wave w owns rows [w*32, w*32+32)
#define NPAD 24                // padded per-node split row (20 + 4 junk)

typedef __attribute__((ext_vector_type(8))) short bf16x8;
typedef __attribute__((ext_vector_type(4))) float f32x4;

__device__ __forceinline__ ushort f2b(float f) {   // f32 -> bf16 RNE (prep only)
    unsigned u = __float_as_uint(f);
    u = (u + 0x7fffu + ((u >> 16) & 1u)) >> 16;
    return (ushort)u;
}
__device__ __forceinline__ float b2f(ushort h) {
    return __uint_as_float(((unsigned)h) << 16);
}
// tanh = 1 - 2/(exp(2x)+1); exact limits at +-inf, no clamps. ~5 VALU ops.
__device__ __forceinline__ float fast_tanh(float x) {
    float e = __builtin_exp2f(x * 2.8853900817779268f);   // exp(2x)
    float r = __builtin_amdgcn_rcpf(e + 1.f);
    return fmaf(-2.f, r, 1.f);
}
__device__ __forceinline__ float fast_sigmoid(float x) {
    float e = __builtin_exp2f(x * -1.4426950408889634f);  // exp(-x)
    return __builtin_amdgcn_rcpf(1.f + e);
}

// ---------- edge preprocessing: group directed edges by src (once/launch) ----------
// directed edge e in [0,E2): src = edges[e] (flat), dst = edges[(e+NEDGES) % E2]
__global__ __launch_bounds__(256) void hist_kernel(const int* __restrict__ edges,
                                                   int* __restrict__ cnt) {
    int e = blockIdx.x * 256 + threadIdx.x;
    if (e < E2) atomicAdd(&cnt[edges[e]], 1);
}

__global__ __launch_bounds__(256) void scan_kernel(const int* __restrict__ cnt,
                                                   int* __restrict__ cursor) {
    __shared__ int part[256];
    int t = threadIdx.x;
    int local[20]; int s = 0;
    int base = t * 20;                      // 256*20 = 5120 >= 5000
    #pragma unroll
    for (int i = 0; i < 20; i++) {
        int idx = base + i;
        int v = (idx < NNODES) ? cnt[idx] : 0;
        local[i] = s; s += v;
    }
    part[t] = s;
    __syncthreads();
    for (int d = 1; d < 256; d <<= 1) {     // Hillis-Steele inclusive scan
        int v = (t >= d) ? part[t - d] : 0;
        __syncthreads();
        part[t] += v;
        __syncthreads();
    }
    int excl = part[t] - s;
    #pragma unroll
    for (int i = 0; i < 20; i++) {
        int idx = base + i;
        if (idx < NNODES) cursor[idx] = excl + local[i];
    }
}

__global__ __launch_bounds__(256) void scatter_kernel(const int* __restrict__ edges,
                                                      int* __restrict__ cursor,
                                                      int* __restrict__ perm) {
    int e = blockIdx.x * 256 + threadIdx.x;
    if (e < E2) {
        int s = edges[e];
        int pos = atomicAdd(&cursor[s], 1);
        perm[pos] = e;
    }
}

// Weights -> split-bf16 (RNE hi + RNE residual), layout [out][k], K padded to 64.
// W1 K-layout matches padded X rows: k<20 = src feats, 24<=k<44 = dst feats, else 0.
__global__ void prep_weights(const float* __restrict__ W1, const float* __restrict__ W2,
                             const float* __restrict__ W3,
                             ushort* __restrict__ W1h, ushort* __restrict__ W1l,
                             ushort* __restrict__ W2h, ushort* __restrict__ W2l,
                             ushort* __restrict__ W3h, ushort* __restrict__ W3l) {
    int t = threadIdx.x;
    for (int i = t; i < 64 * 64; i += 256) {
        int n = i >> 6, k = i & 63;
        float v = 0.f;
        if (k < NFEAT)                          v = W1[n * (2 * NFEAT) + k];
        else if (k >= NPAD && k < NPAD + NFEAT) v = W1[n * (2 * NFEAT) + NFEAT + (k - NPAD)];
        ushort h = f2b(v);
        W1h[i] = h; W1l[i] = f2b(v - b2f(h));
    }
    for (int i = t; i < 64 * 64; i += 256) {
        float v = W2[i];
        ushort h = f2b(v);
        W2h[i] = h; W2l[i] = f2b(v - b2f(h));
    }
    for (int i = t; i < 32 * 64; i += 256) {
        int n = i >> 6, k = i & 63;
        float v = (n < EFEAT) ? W3[n * HID + k] : 0.f;
        ushort h = f2b(v);
        W3h[i] = h; W3l[i] = f2b(v - b2f(h));
    }
}

// Initial per-node truncation split (iteration 0); later iters come from gru_kernel.
__global__ __launch_bounds__(256) void split_nf(const float* __restrict__ nf,
                                                ushort* __restrict__ nfh,
                                                ushort* __restrict__ nfl) {
    int gid = blockIdx.x * 256 + threadIdx.x;
    if (gid >= NENV * NNODES) return;
    const float* p = nf + (size_t)gid * NFEAT;
    ushort* ph = nfh + (size_t)gid * NPAD;
    ushort* pl = nfl + (size_t)gid * NPAD;
    #pragma unroll
    for (int k = 0; k < NFEAT; k++) {
        float v = p[k];
        unsigned u = __float_as_uint(v);
        ph[k] = (ushort)(u >> 16);                      // truncated hi
        float lo = v - __uint_as_float(u & 0xffff0000u);
        pl[k] = (ushort)(__float_as_uint(lo) >> 16);    // truncated lo (~2^-17 repr err)
    }
    *(uint2*)(ph + NFEAT) = make_uint2(0u, 0u);         // zero pad cols 20..23
    *(uint2*)(pl + NFEAT) = make_uint2(0u, 0u);
}

// 128 SORTED edge-rows/block, 4 waves, wave w owns rows [w*32,w*32+32) — all
// LDS traffic wave-local => NO barriers. A = X (LDS, swizzled), B = W (L1-hot).
// Split-bf16 compensated: acc = Xh*Wh + Xl*Wh + Xh*Wl per K-tile.
// GEMM3 writes msgs to the wave's own (consumed) LDS slice, then a segmented
// scan (rows sorted by src) emits ~1 atomicAdd per (segment,col).
// NOTE: no __shfl inside divergent code — keys pass through LDS (col 24).
__global__ __launch_bounds__(THREADS) void edge_mlp_mfma(
    const ushort* __restrict__ nfh, const ushort* __restrict__ nfl,
    const int*   __restrict__ edges, const int* __restrict__ perm,
    const ushort* __restrict__ W1h, const ushort* __restrict__ W1l,
    const ushort* __restrict__ W2h, const ushort* __restrict__ W2l,
    const ushort* __restrict__ W3h, const ushort* __restrict__ W3l,
    const float* __restrict__ b1, const float* __restrict__ b2,
    const float* __restrict__ b3,
    float* __restrict__ store)
{
    __shared__ bf16x8 smem[2048];                 // 32 KB single buffer
    bf16x8* Ahi = smem;                           // 16 KB: X->H1->H2 (hi)
    bf16x8* Alo = smem + 1024;                    // 16 KB: (lo)
    ushort* Ahi16 = (ushort*)Ahi; ushort* Alo16 = (ushort*)Alo;
    float*  msgf  = (float*)smem;                 // GEMM3 overlay, per-wave slice
    int*    msgi  = (int*)smem;                   // int view (for keys)

    const int tid = threadIdx.x;

    // ---- gather: 2 threads per edge row (src half / dst half), pure copy ----
    {
        int row  = tid >> 1, half = tid & 1;
        int grow = blockIdx.x * ROWS + row;
        int env  = grow / E2;
        int sr   = grow - env * E2;
        int e    = perm[sr];
        int node;
        if (half == 0) node = edges[e];                      // src
        else { int di = e + NEDGES; if (di >= E2) di -= E2; node = edges[di]; }  // dst
        const bf16x8* nh = (const bf16x8*)(nfh + ((size_t)env * NNODES + node) * NPAD);
        const bf16x8* nl = (const bf16x8*)(nfl + ((size_t)env * NNODES + node) * NPAD);
        int rb = row * 8, sw = row & 7, g0 = half * 3;
        Ahi[rb + ((g0 + 0) ^ sw)] = nh[0]; Alo[rb + ((g0 + 0) ^ sw)] = nl[0];
        Ahi[rb + ((g0 + 1) ^ sw)] = nh[1]; Alo[rb + ((g0 + 1) ^ sw)] = nl[1];
        Ahi[rb + ((g0 + 2) ^ sw)] = nh[2]; Alo[rb + ((g0 + 2) ^ sw)] = nl[2];
        if (half) {
            bf16x8 z = {0,0,0,0,0,0,0,0};
            Ahi[rb + (6 ^ sw)] = z; Alo[rb + (6 ^ sw)] = z;
            Ahi[rb + (7 ^ sw)] = z; Alo[rb + (7 ^ sw)] = z;
        }
    }

    const int wave = tid >> 6;
    const int lane = tid & 63;
    const int lr   = lane & 15;      // A-row-in-tile / B-col / C-col
    const int kg   = lane >> 4;      // k-group for A/B; C row-group
    const int m0   = wave * 32;

#define MFMA6(acc, a0h, a0l, a1h, a1l, bh0, bl0, bh1, bl1)                          \
    acc = __builtin_amdgcn_mfma_f32_16x16x32_bf16(a0h, bh0, acc, 0, 0, 0);          \
    acc = __builtin_amdgcn_mfma_f32_16x16x32_bf16(a0l, bh0, acc, 0, 0, 0);          \
    acc = __builtin_amdgcn_mfma_f32_16x16x32_bf16(a0h, bl0, acc, 0, 0, 0);          \
    acc = __builtin_amdgcn_mfma_f32_16x16x32_bf16(a1h, bh1, acc, 0, 0, 0);          \
    acc = __builtin_amdgcn_mfma_f32_16x16x32_bf16(a1l, bh1, acc, 0, 0, 0);          \
    acc = __builtin_amdgcn_mfma_f32_16x16x32_bf16(a1h, bl1, acc, 0, 0, 0);

#define GEMM_LAYER(Wh, Wl, bias)                                                    \
    {                                                                               \
        bf16x8 wh[4][2], wl[4][2];                                                  \
        float bb[4];                                                                \
        _Pragma("unroll")                                                           \
        for (int n = 0; n < 4; n++) {                                               \
            _Pragma("unroll")                                                       \
            for (int kt = 0; kt < 2; kt++) {                                        \
                wh[n][kt] = *(const bf16x8*)(Wh + (n * 16 + lr) * 64 + kt * 32 + kg * 8); \
                wl[n][kt] = *(const bf16x8*)(Wl + (n * 16 + lr) * 64 + kt * 32 + kg * 8); \
            }                                                                       \
            bb[n] = bias[n * 16 + lr];                                              \
        }                                                                           \
        _Pragma("unroll")                                                           \
        for (int m = 0; m < 2; m++) {                                               \
            int arow = m0 + m * 16 + lr, sw = arow & 7;                             \
            bf16x8 a0h = Ahi[arow * 8 + (kg ^ sw)];                                 \
            bf16x8 a0l = Alo[arow * 8 + (kg ^ sw)];                                 \
            bf16x8 a1h = Ahi[arow * 8 + ((4 + kg) ^ sw)];                           \
            bf16x8 a1l = Alo[arow * 8 + ((4 + kg) ^ sw)];                           \
            f32x4 acc[4];                                                           \
            _Pragma("unroll")                                                       \
            for (int n = 0; n < 4; n++) {                                           \
                acc[n] = f32x4{bb[n], bb[n], bb[n], bb[n]};                         \
                MFMA6(acc[n], a0h, a0l, a1h, a1l, wh[n][0], wl[n][0], wh[n][1], wl[n][1]) \
            }                                                                       \
            _Pragma("unroll")                                                       \
            for (int n = 0; n < 4; n++) {                                           \
                int col = n * 16 + lr;                                              \
                _Pragma("unroll")                                                   \
                for (int r = 0; r < 4; r++) {                                       \
                    int row = m0 + m * 16 + kg * 4 + r;                             \
                    float t = fast_tanh(acc[n][r]);                                 \
                    unsigned u = __float_as_uint(t);                                \
                    int idx = row * 64 + (col ^ ((row & 7) << 3));                  \
                    Ahi16[idx] = (ushort)(u >> 16);                                 \
                    float lo = t - __uint_as_float(u & 0xffff0000u);                \
                    Alo16[idx] = (ushort)(__float_as_uint(lo) >> 16);               \
                }                                                                   \
            }                                                                       \
        }                                                                           \
    }

    GEMM_LAYER(W1h, W1l, b1)   // X  -> H1 (in place)
    GEMM_LAYER(W2h, W2l, b2)   // H1 -> H2 (in place)

    // ---- GEMM3 + segmented reduction ----
    {
        // per-lane key for this wave's 32 rows: lane i (i=lane&31) -> row m0+i
        int i_ = lane & 31;
        int grow_i = blockIdx.x * ROWS + m0 + i_;
        int env_i  = grow_i / E2;
        int sr_i   = grow_i - env_i * E2;
        int key    = env_i * NNODES + edges[perm[sr_i]];     // (env,src) id

        bf16x8 wh[2][2], wl[2][2];
        #pragma unroll
        for (int n = 0; n < 2; n++)
            #pragma unroll
            for (int kt = 0; kt < 2; kt++) {
                wh[n][kt] = *(const bf16x8*)(W3h + (n * 16 + lr) * 64 + kt * 32 + kg * 8);
                wl[n][kt] = *(const bf16x8*)(W3l + (n * 16 + lr) * 64 + kt * 32 + kg * 8);
            }
        float bb0 = b3[lr];
        float bb1 = (lr < 4) ? b3[16 + lr] : 0.f;

        // load ALL A fragments first (msg overlay will overwrite this slice)
        f32x4 acc0[2], acc1[2];
        #pragma unroll
        for (int m = 0; m < 2; m++) {
            int arow = m0 + m * 16 + lr, sw = arow & 7;
            bf16x8 a0h = Ahi[arow * 8 + (kg ^ sw)];
            bf16x8 a0l = Alo[arow * 8 + (kg ^ sw)];
            bf16x8 a1h = Ahi[arow * 8 + ((4 + kg) ^ sw)];
            bf16x8 a1l = Alo[arow * 8 + ((4 + kg) ^ sw)];
            acc0[m] = f32x4{bb0, bb0, bb0, bb0};
            acc1[m] = f32x4{bb1, bb1, bb1, bb1};
            MFMA6(acc0[m], a0h, a0l, a1h, a1l, wh[0][0], wl[0][0], wh[0][1], wl[0][1])
            MFMA6(acc1[m], a0h, a0l, a1h, a1l, wh[1][0], wl[1][0], wh[1][1], wl[1][1])
        }

        // write f32 msgs into the wave's OWN slice (rows m0..m0+31 consumed)
        // layout: word = wave*1024 + lrow*25 + col; col 24 holds the row key.
        int wbase = wave * 1024;
        #pragma unroll
        for (int m = 0; m < 2; m++) {
            #pragma unroll
            for (int r = 0; r < 4; r++) {
                int lrow = m * 16 + kg * 4 + r;
                msgf[wbase + lrow * 25 + lr] = acc0[m][r];
                if (lr < 4) msgf[wbase + lrow * 25 + 16 + lr] = acc1[m][r];
            }
        }
        if (lane < 32) msgi[wbase + lane * 25 + 24] = key;   // key per row, via LDS

        // segment-boundary flags (FULL exec: shfl/ballot legal here)
        int nxt = __shfl_down(key, 1);
        bool flag = (i_ == 31) || (key != nxt);
        unsigned fm = (unsigned)__ballot(flag);              // bits 0..31 valid

        if (lane < EFEAT) {
            int c = lane;
            float sum = 0.f;
            for (int i = 0; i < 32; i++) {
                sum += msgf[wbase + i * 25 + c];
                if ((fm >> i) & 1u) {
                    int curk = msgi[wbase + i * 25 + 24];    // LDS read, no shfl
                    atomicAdd(store + (size_t)curk * EFEAT + c, sum);
                    sum = 0.f;
                }
            }
        }
    }
#undef GEMM_LAYER
#undef MFMA6
}

// GRU single step per (env,node); emits f32 nf AND next iteration's split planes.
__global__ __launch_bounds__(256) void gru_kernel(
    const float* __restrict__ store,
    const float* __restrict__ Wih, const float* __restrict__ bih,
    const float* __restrict__ Whh, const float* __restrict__ bhh,
    float* __restrict__ nf,
    ushort* __restrict__ nfh, ushort* __restrict__ nfl)
{
    int gid = blockIdx.x * blockDim.x + threadIdx.x;
    const int total = NENV * NNODES;
    if (gid >= total) return;

    const float* s = store + (size_t)gid * EFEAT;
    float*       h = nf    + (size_t)gid * NFEAT;
    ushort*     ph = nfh   + (size_t)gid * NPAD;
    ushort*     pl = nfl   + (size_t)gid * NPAD;

    float sv[EFEAT], hv[NFEAT];
    #pragma unroll
    for (int k = 0; k < EFEAT; k++) sv[k] = s[k];
    #pragma unroll
    for (int k = 0; k < NFEAT; k++) hv[k] = h[k];

    for (int t = 0; t < NFEAT; t++) {
        float ir = bih[t],            hr = bhh[t];
        float iz = bih[NFEAT + t],    hz = bhh[NFEAT + t];
        float in_ = bih[2*NFEAT + t], hn = bhh[2*NFEAT + t];
        const float* wr = Wih + t * EFEAT;
        const float* wz = Wih + (NFEAT + t) * EFEAT;
        const float* wn = Wih + (2*NFEAT + t) * EFEAT;
        #pragma unroll
        for (int k = 0; k < EFEAT; k++) {
            ir  = fmaf(sv[k], wr[k], ir);
            iz  = fmaf(sv[k], wz[k], iz);
            in_ = fmaf(sv[k], wn[k], in_);
        }
        const float* vr = Whh + t * NFEAT;
        const float* vz = Whh + (NFEAT + t) * NFEAT;
        const float* vn = Whh + (2*NFEAT + t) * NFEAT;
        #pragma unroll
        for (int k = 0; k < NFEAT; k++) {
            hr = fmaf(hv[k], vr[k], hr);
            hz = fmaf(hv[k], vz[k], hz);
            hn = fmaf(hv[k], vn[k], hn);
        }
        float r = fast_sigmoid(ir + hr);
        float z = fast_sigmoid(iz + hz);
        float n = fast_tanh(in_ + r * hn);
        float hw = (1.f - z) * n + z * hv[t];
        h[t] = hw;
        unsigned u = __float_as_uint(hw);
        ph[t] = (ushort)(u >> 16);
        float lo = hw - __uint_as_float(u & 0xffff0000u);
        pl[t] = (ushort)(__float_as_uint(lo) >> 16);
    }
    *(uint2*)(ph + NFEAT) = make_uint2(0u, 0u);
    *(uint2*)(pl + NFEAT) = make_uint2(0u, 0u);
}

extern "C" void kernel_launch(void* const* d_in, const int* in_sizes, int n_in,
                              void* d_out, int out_size, void* d_ws, size_t ws_size,
                              hipStream_t stream) {
    const float* nf_in = (const float*)d_in[0];
    const int*   edges = (const int*)d_in[1];
    const float* W1 = (const float*)d_in[2];
    const float* b1 = (const float*)d_in[3];
    const float* W2 = (const float*)d_in[4];
    const float* b2 = (const float*)d_in[5];
    const float* W3 = (const float*)d_in[6];
    const float* b3 = (const float*)d_in[7];
    const float* Wih = (const float*)d_in[8];
    const float* Whh = (const float*)d_in[9];
    const float* bih = (const float*)d_in[10];
    const float* bhh = (const float*)d_in[11];

    float* nf    = (float*)d_out;
    float* store = (float*)d_ws;
    const size_t nf_bytes    = (size_t)NENV * NNODES * NFEAT * sizeof(float);
    const size_t store_bytes = (size_t)NENV * NNODES * EFEAT * sizeof(float);
    // ws layout: store | W splits | nfh | nfl | cnt | cursor | perm  (~14.6 MB)
    ushort* W1h = (ushort*)((char*)d_ws + store_bytes);
    ushort* W1l = W1h + 64 * 64;
    ushort* W2h = W1l + 64 * 64;
    ushort* W2l = W2h + 64 * 64;
    ushort* W3h = W2l + 64 * 64;
    ushort* W3l = W3h + 32 * 64;
    ushort* nfh = W3l + 32 * 64;
    ushort* nfl = nfh + (size_t)NENV * NNODES * NPAD;
    int* cnt    = (int*)(nfl + (size_t)NENV * NNODES * NPAD);
    int* cursor = cnt + NNODES;
    int* perm   = cursor + NNODES;

    // --- once per launch: weights, initial split, edge grouping by src ---
    prep_weights<<<1, 256, 0, stream>>>(W1, W2, W3, W1h, W1l, W2h, W2l, W3h, W3l);
    split_nf<<<(NENV * NNODES + 255) / 256, 256, 0, stream>>>(nf_in, nfh, nfl);
    hipMemcpyAsync(nf, nf_in, nf_bytes, hipMemcpyDeviceToDevice, stream);
    hipMemsetAsync(cnt, 0, NNODES * sizeof(int), stream);
    hist_kernel<<<(E2 + 255) / 256, 256, 0, stream>>>(edges, cnt);
    scan_kernel<<<1, 256, 0, stream>>>(cnt, cursor);
    scatter_kernel<<<(E2 + 255) / 256, 256, 0, stream>>>(edges, cursor, perm);

    const int edge_blocks = (NENV * E2) / ROWS;           // 12500, exact
    dim3 grid_n((NENV * NNODES + 255) / 256);

    for (int it = 0; it < ITERS; it++) {
        hipMemsetAsync(store, 0, store_bytes, stream);
        edge_mlp_mfma<<<edge_blocks, THREADS, 0, stream>>>(nfh, nfl, edges, perm,
                                                           W1h, W1l, W2h, W2l, W3h, W3l,
                                                           b1, b2, b3, store);
        gru_kernel<<<grid_n, 256, 0, stream>>>(store, Wih, bih, Whh, bhh, nf, nfh, nfl);
    }
}

// Round 11
// 948.435 us; speedup vs baseline: 3.1115x; 1.1178x over previous
//
#include <hip/hip_runtime.h>

#define NFEAT 20
#define EFEAT 20
#define HID   64
#define NENV  16
#define NNODES 5000
#define NEDGES 50000
#define E2 (2*NEDGES)          // 100000 directed edges
#define ITERS 3
#define ROWS 128               // edge rows per block
#define THREADS 256            // 4 waves; wave w owns rows [w*32, w*32+32)
#define NPAD 24                // padded per-node split row (20 + 4 junk) = 3 x 8-chunks

typedef __attribute__((ext_vector_type(8))) short bf16x8;
typedef __attribute__((ext_vector_type(4))) float f32x4;

__device__ __forceinline__ ushort f2b(float f) {   // f32 -> bf16 RNE (prep only)
    unsigned u = __float_as_uint(f);
    u = (u + 0x7fffu + ((u >> 16) & 1u)) >> 16;
    return (ushort)u;
}
__device__ __forceinline__ float b2f(ushort h) {
    return __uint_as_float(((unsigned)h) << 16);
}
// tanh = 1 - 2/(exp(2x)+1); exact limits at +-inf, no clamps. ~5 VALU ops.
__device__ __forceinline__ float fast_tanh(float x) {
    float e = __builtin_exp2f(x * 2.8853900817779268f);   // exp(2x)
    float r = __builtin_amdgcn_rcpf(e + 1.f);
    return fmaf(-2.f, r, 1.f);
}
__device__ __forceinline__ float fast_sigmoid(float x) {
    float e = __builtin_exp2f(x * -1.4426950408889634f);  // exp(-x)
    return __builtin_amdgcn_rcpf(1.f + e);
}

// ---------- edge preprocessing: group directed edges by src (once/launch) ----------
// directed edge e in [0,E2): src = edges[e] (flat), dst = edges[(e+NEDGES) % E2]
__global__ __launch_bounds__(256) void hist_kernel(const int* __restrict__ edges,
                                                   int* __restrict__ cnt) {
    int e = blockIdx.x * 256 + threadIdx.x;
    if (e < E2) atomicAdd(&cnt[edges[e]], 1);
}

__global__ __launch_bounds__(256) void scan_kernel(const int* __restrict__ cnt,
                                                   int* __restrict__ cursor) {
    __shared__ int part[256];
    int t = threadIdx.x;
    int local[20]; int s = 0;
    int base = t * 20;                      // 256*20 = 5120 >= 5000
    #pragma unroll
    for (int i = 0; i < 20; i++) {
        int idx = base + i;
        int v = (idx < NNODES) ? cnt[idx] : 0;
        local[i] = s; s += v;
    }
    part[t] = s;
    __syncthreads();
    for (int d = 1; d < 256; d <<= 1) {     // Hillis-Steele inclusive scan
        int v = (t >= d) ? part[t - d] : 0;
        __syncthreads();
        part[t] += v;
        __syncthreads();
    }
    int excl = part[t] - s;
    #pragma unroll
    for (int i = 0; i < 20; i++) {
        int idx = base + i;
        if (idx < NNODES) cursor[idx] = excl + local[i];
    }
}

// emits src-sorted node-id arrays: snode[pos], dnode[pos] (shared by all envs)
__global__ __launch_bounds__(256) void scatter_kernel(const int* __restrict__ edges,
                                                      int* __restrict__ cursor,
                                                      int* __restrict__ snode,
                                                      int* __restrict__ dnode) {
    int e = blockIdx.x * 256 + threadIdx.x;
    if (e < E2) {
        int s = edges[e];
        int di = e + NEDGES; if (di >= E2) di -= E2;
        int d = edges[di];
        int pos = atomicAdd(&cursor[s], 1);
        snode[pos] = s;
        dnode[pos] = d;
    }
}

// Weights -> split-bf16 (RNE hi + RNE residual), layout [out][k], K padded to 64.
// W1 K-layout matches padded X rows: k<20 = src feats, 24<=k<44 = dst feats, else 0.
__global__ void prep_weights(const float* __restrict__ W1, const float* __restrict__ W2,
                             const float* __restrict__ W3,
                             ushort* __restrict__ W1h, ushort* __restrict__ W1l,
                             ushort* __restrict__ W2h, ushort* __restrict__ W2l,
                             ushort* __restrict__ W3h, ushort* __restrict__ W3l) {
    int t = threadIdx.x;
    for (int i = t; i < 64 * 64; i += 256) {
        int n = i >> 6, k = i & 63;
        float v = 0.f;
        if (k < NFEAT)                          v = W1[n * (2 * NFEAT) + k];
        else if (k >= NPAD && k < NPAD + NFEAT) v = W1[n * (2 * NFEAT) + NFEAT + (k - NPAD)];
        ushort h = f2b(v);
        W1h[i] = h; W1l[i] = f2b(v - b2f(h));
    }
    for (int i = t; i < 64 * 64; i += 256) {
        float v = W2[i];
        ushort h = f2b(v);
        W2h[i] = h; W2l[i] = f2b(v - b2f(h));
    }
    for (int i = t; i < 32 * 64; i += 256) {
        int n = i >> 6, k = i & 63;
        float v = (n < EFEAT) ? W3[n * HID + k] : 0.f;
        ushort h = f2b(v);
        W3h[i] = h; W3l[i] = f2b(v - b2f(h));
    }
}

// Initial per-node truncation split (iteration 0); later iters come from gru_kernel.
__global__ __launch_bounds__(256) void split_nf(const float* __restrict__ nf,
                                                ushort* __restrict__ nfh,
                                                ushort* __restrict__ nfl) {
    int gid = blockIdx.x * 256 + threadIdx.x;
    if (gid >= NENV * NNODES) return;
    const float* p = nf + (size_t)gid * NFEAT;
    ushort* ph = nfh + (size_t)gid * NPAD;
    ushort* pl = nfl + (size_t)gid * NPAD;
    #pragma unroll
    for (int k = 0; k < NFEAT; k++) {
        float v = p[k];
        unsigned u = __float_as_uint(v);
        ph[k] = (ushort)(u >> 16);                      // truncated hi
        float lo = v - __uint_as_float(u & 0xffff0000u);
        pl[k] = (ushort)(__float_as_uint(lo) >> 16);    // truncated lo (~2^-17 repr err)
    }
    *(uint2*)(ph + NFEAT) = make_uint2(0u, 0u);         // zero pad cols 20..23
    *(uint2*)(pl + NFEAT) = make_uint2(0u, 0u);
}

// 128 SORTED edge-rows/block, 4 waves, wave w owns rows [w*32,w*32+32) — all
// LDS traffic wave-local => NO barriers.
// GEMM1: A-fragments loaded DIRECTLY from global split planes (NPAD=24 makes
// every 8-elem fragment chunk a 16B-aligned slice of a node row, or zero) —
// no gather phase, no X staging in LDS. Sorted rows => L1/L2-hot loads.
// GEMM2/3: A from LDS H planes (split, swizzled). Split-bf16 compensated MFMA.
// GEMM3 writes msgs to the wave's own LDS slice; segmented scan -> ~1 atomic
// per (segment,col). No __shfl inside divergent code (keys via LDS col 24).
__global__ __launch_bounds__(THREADS) void edge_mlp_mfma(
    const ushort* __restrict__ nfh, const ushort* __restrict__ nfl,
    const int*   __restrict__ snode, const int* __restrict__ dnode,
    const ushort* __restrict__ W1h, const ushort* __restrict__ W1l,
    const ushort* __restrict__ W2h, const ushort* __restrict__ W2l,
    const ushort* __restrict__ W3h, const ushort* __restrict__ W3l,
    const float* __restrict__ b1, const float* __restrict__ b2,
    const float* __restrict__ b3,
    float* __restrict__ store)
{
    __shared__ bf16x8 smem[2048];                 // 32 KB
    bf16x8* Hhi = smem;                           // 16 KB: h1 -> h2 (hi), swizzled
    bf16x8* Hlo = smem + 1024;                    // 16 KB: (lo)
    ushort* Hhi16 = (ushort*)Hhi; ushort* Hlo16 = (ushort*)Hlo;
    float*  msgf  = (float*)smem;                 // GEMM3 overlay, per-wave slice
    int*    msgi  = (int*)smem;                   // int view (keys)

    const int tid  = threadIdx.x;
    const int wave = tid >> 6;
    const int lane = tid & 63;
    const int lr   = lane & 15;      // A-row-in-tile / B-col / C-col
    const int kg   = lane >> 4;      // k-group for A/B; C row-group
    const int m0   = wave * 32;

#define MFMA6(acc, a0h, a0l, a1h, a1l, bh0, bl0, bh1, bl1)                          \
    acc = __builtin_amdgcn_mfma_f32_16x16x32_bf16(a0h, bh0, acc, 0, 0, 0);          \
    acc = __builtin_amdgcn_mfma_f32_16x16x32_bf16(a0l, bh0, acc, 0, 0, 0);          \
    acc = __builtin_amdgcn_mfma_f32_16x16x32_bf16(a0h, bl0, acc, 0, 0, 0);          \
    acc = __builtin_amdgcn_mfma_f32_16x16x32_bf16(a1h, bh1, acc, 0, 0, 0);          \
    acc = __builtin_amdgcn_mfma_f32_16x16x32_bf16(a1l, bh1, acc, 0, 0, 0);          \
    acc = __builtin_amdgcn_mfma_f32_16x16x32_bf16(a1h, bl1, acc, 0, 0, 0);

    // epilogue helper: tanh + truncation split -> H planes (swizzled b16 writes)
#define STORE_H(acc, n_)                                                            \
    {                                                                               \
        int col = (n_) * 16 + lr;                                                   \
        _Pragma("unroll")                                                           \
        for (int r = 0; r < 4; r++) {                                               \
            int row = m0 + m * 16 + kg * 4 + r;                                     \
            float t = fast_tanh(acc[r]);                                            \
            unsigned u = __float_as_uint(t);                                        \
            int idx = row * 64 + (col ^ ((row & 7) << 3));                          \
            Hhi16[idx] = (ushort)(u >> 16);                                         \
            float lo = t - __uint_as_float(u & 0xffff0000u);                        \
            Hlo16[idx] = (ushort)(__float_as_uint(lo) >> 16);                       \
        }                                                                           \
    }

    // ---- GEMM1: X (direct-global, split) @ W1^T +b1, tanh -> H (split, LDS) ----
    {
        bf16x8 wh[4][2], wl[4][2];
        float bb[4];
        #pragma unroll
        for (int n = 0; n < 4; n++) {
            #pragma unroll
            for (int kt = 0; kt < 2; kt++) {
                wh[n][kt] = *(const bf16x8*)(W1h + (n * 16 + lr) * 64 + kt * 32 + kg * 8);
                wl[n][kt] = *(const bf16x8*)(W1l + (n * 16 + lr) * 64 + kt * 32 + kg * 8);
            }
            bb[n] = b1[n * 16 + lr];
        }
        #pragma unroll
        for (int m = 0; m < 2; m++) {
            int rr = m0 + m * 16 + lr;
            int gr = blockIdx.x * ROWS + rr;
            int env = gr / E2;
            int sr  = gr - env * E2;
            int sn  = env * NNODES + snode[sr];
            int dn  = env * NNODES + dnode[sr];
            const ushort* shp = nfh + (size_t)sn * NPAD;
            const ushort* slp = nfl + (size_t)sn * NPAD;
            const ushort* dhp = nfh + (size_t)dn * NPAD;
            const ushort* dlp = nfl + (size_t)dn * NPAD;
            // kt0 chunks: kg<3 -> src chunk kg ; kg==3 -> dst chunk 0
            // kt1 chunks: kg<2 -> dst chunk 1+kg ; else zero
            bf16x8 a0h, a0l, a1h, a1l;
            if (kg < 3) { a0h = *(const bf16x8*)(shp + kg * 8);
                          a0l = *(const bf16x8*)(slp + kg * 8); }
            else        { a0h = *(const bf16x8*)(dhp);
                          a0l = *(const bf16x8*)(dlp); }
            if (kg < 2) { a1h = *(const bf16x8*)(dhp + 8 + kg * 8);
                          a1l = *(const bf16x8*)(dlp + 8 + kg * 8); }
            else        { bf16x8 z = {0,0,0,0,0,0,0,0}; a1h = z; a1l = z; }
            f32x4 acc[4];
            #pragma unroll
            for (int n = 0; n < 4; n++) {
                acc[n] = f32x4{bb[n], bb[n], bb[n], bb[n]};
                MFMA6(acc[n], a0h, a0l, a1h, a1l, wh[n][0], wl[n][0], wh[n][1], wl[n][1])
            }
            #pragma unroll
            for (int n = 0; n < 4; n++) STORE_H(acc[n], n)
        }
    }

    // ---- GEMM2: H1 (LDS, split) @ W2^T +b2, tanh -> H2 (in place) ----
    {
        bf16x8 wh[4][2], wl[4][2];
        float bb[4];
        #pragma unroll
        for (int n = 0; n < 4; n++) {
            #pragma unroll
            for (int kt = 0; kt < 2; kt++) {
                wh[n][kt] = *(const bf16x8*)(W2h + (n * 16 + lr) * 64 + kt * 32 + kg * 8);
                wl[n][kt] = *(const bf16x8*)(W2l + (n * 16 + lr) * 64 + kt * 32 + kg * 8);
            }
            bb[n] = b2[n * 16 + lr];
        }
        #pragma unroll
        for (int m = 0; m < 2; m++) {
            int arow = m0 + m * 16 + lr, sw = arow & 7;
            bf16x8 a0h = Hhi[arow * 8 + (kg ^ sw)];
            bf16x8 a0l = Hlo[arow * 8 + (kg ^ sw)];
            bf16x8 a1h = Hhi[arow * 8 + ((4 + kg) ^ sw)];
            bf16x8 a1l = Hlo[arow * 8 + ((4 + kg) ^ sw)];
            f32x4 acc[4];
            #pragma unroll
            for (int n = 0; n < 4; n++) {
                acc[n] = f32x4{bb[n], bb[n], bb[n], bb[n]};
                MFMA6(acc[n], a0h, a0l, a1h, a1l, wh[n][0], wl[n][0], wh[n][1], wl[n][1])
            }
            #pragma unroll
            for (int n = 0; n < 4; n++) STORE_H(acc[n], n)
        }
    }

    // ---- GEMM3 + segmented reduction ----
    {
        int i_ = lane & 31;
        int gr_i  = blockIdx.x * ROWS + m0 + i_;
        int env_i = gr_i / E2;
        int sr_i  = gr_i - env_i * E2;
        int key   = env_i * NNODES + snode[sr_i];            // full store row id

        bf16x8 wh[2][2], wl[2][2];
        #pragma unroll
        for (int n = 0; n < 2; n++)
            #pragma unroll
            for (int kt = 0; kt < 2; kt++) {
                wh[n][kt] = *(const bf16x8*)(W3h + (n * 16 + lr) * 64 + kt * 32 + kg * 8);
                wl[n][kt] = *(const bf16x8*)(W3l + (n * 16 + lr) * 64 + kt * 32 + kg * 8);
            }
        float bb0 = b3[lr];
        float bb1 = (lr < 4) ? b3[16 + lr] : 0.f;

        // load ALL A fragments first (msg overlay will overwrite this slice)
        f32x4 acc0[2], acc1[2];
        #pragma unroll
        for (int m = 0; m < 2; m++) {
            int arow = m0 + m * 16 + lr, sw = arow & 7;
            bf16x8 a0h = Hhi[arow * 8 + (kg ^ sw)];
            bf16x8 a0l = Hlo[arow * 8 + (kg ^ sw)];
            bf16x8 a1h = Hhi[arow * 8 + ((4 + kg) ^ sw)];
            bf16x8 a1l = Hlo[arow * 8 + ((4 + kg) ^ sw)];
            acc0[m] = f32x4{bb0, bb0, bb0, bb0};
            acc1[m] = f32x4{bb1, bb1, bb1, bb1};
            MFMA6(acc0[m], a0h, a0l, a1h, a1l, wh[0][0], wl[0][0], wh[0][1], wl[0][1])
            MFMA6(acc1[m], a0h, a0l, a1h, a1l, wh[1][0], wl[1][0], wh[1][1], wl[1][1])
        }

        // write f32 msgs into the wave's OWN slice (rows m0..m0+31 consumed)
        // layout: word = wave*1024 + lrow*25 + col; col 24 holds the row key.
        int wbase = wave * 1024;
        #pragma unroll
        for (int m = 0; m < 2; m++) {
            #pragma unroll
            for (int r = 0; r < 4; r++) {
                int lrow = m * 16 + kg * 4 + r;
                msgf[wbase + lrow * 25 + lr] = acc0[m][r];
                if (lr < 4) msgf[wbase + lrow * 25 + 16 + lr] = acc1[m][r];
            }
        }
        if (lane < 32) msgi[wbase + lane * 25 + 24] = key;   // key per row, via LDS

        // segment-boundary flags (FULL exec: shfl/ballot legal here)
        int nxt = __shfl_down(key, 1);
        bool flag = (i_ == 31) || (key != nxt);
        unsigned fm = (unsigned)__ballot(flag);              // bits 0..31 valid

        if (lane < EFEAT) {
            int c = lane;
            float sum = 0.f;
            for (int i = 0; i < 32; i++) {
                sum += msgf[wbase + i * 25 + c];
                if ((fm >> i) & 1u) {
                    int curk = msgi[wbase + i * 25 + 24];    // LDS read, no shfl
                    atomicAdd(store + (size_t)curk * EFEAT + c, sum);
                    sum = 0.f;
                }
            }
        }
    }
#undef STORE_H
#undef MFMA6
}

// GRU single step per (env,node); emits f32 nf AND next iteration's split planes.
__global__ __launch_bounds__(256) void gru_kernel(
    const float* __restrict__ store,
    const float* __restrict__ Wih, const float* __restrict__ bih,
    const float* __restrict__ Whh, const float* __restrict__ bhh,
    float* __restrict__ nf,
    ushort* __restrict__ nfh, ushort* __restrict__ nfl)
{
    int gid = blockIdx.x * blockDim.x + threadIdx.x;
    const int total = NENV * NNODES;
    if (gid >= total) return;

    const float* s = store + (size_t)gid * EFEAT;
    float*       h = nf    + (size_t)gid * NFEAT;
    ushort*     ph = nfh   + (size_t)gid * NPAD;
    ushort*     pl = nfl   + (size_t)gid * NPAD;

    float sv[EFEAT], hv[NFEAT];
    #pragma unroll
    for (int k = 0; k < EFEAT; k++) sv[k] = s[k];
    #pragma unroll
    for (int k = 0; k < NFEAT; k++) hv[k] = h[k];

    for (int t = 0; t < NFEAT; t++) {
        float ir = bih[t],            hr = bhh[t];
        float iz = bih[NFEAT + t],    hz = bhh[NFEAT + t];
        float in_ = bih[2*NFEAT + t], hn = bhh[2*NFEAT + t];
        const float* wr = Wih + t * EFEAT;
        const float* wz = Wih + (NFEAT + t) * EFEAT;
        const float* wn = Wih + (2*NFEAT + t) * EFEAT;
        #pragma unroll
        for (int k = 0; k < EFEAT; k++) {
            ir  = fmaf(sv[k], wr[k], ir);
            iz  = fmaf(sv[k], wz[k], iz);
            in_ = fmaf(sv[k], wn[k], in_);
        }
        const float* vr = Whh + t * NFEAT;
        const float* vz = Whh + (NFEAT + t) * NFEAT;
        const float* vn = Whh + (2*NFEAT + t) * NFEAT;
        #pragma unroll
        for (int k = 0; k < NFEAT; k++) {
            hr = fmaf(hv[k], vr[k], hr);
            hz = fmaf(hv[k], vz[k], hz);
            hn = fmaf(hv[k], vn[k], hn);
        }
        float r = fast_sigmoid(ir + hr);
        float z = fast_sigmoid(iz + hz);
        float n = fast_tanh(in_ + r * hn);
        float hw = (1.f - z) * n + z * hv[t];
        h[t] = hw;
        unsigned u = __float_as_uint(hw);
        ph[t] = (ushort)(u >> 16);
        float lo = hw - __uint_as_float(u & 0xffff0000u);
        pl[t] = (ushort)(__float_as_uint(lo) >> 16);
    }
    *(uint2*)(ph + NFEAT) = make_uint2(0u, 0u);
    *(uint2*)(pl + NFEAT) = make_uint2(0u, 0u);
}

extern "C" void kernel_launch(void* const* d_in, const int* in_sizes, int n_in,
                              void* d_out, int out_size, void* d_ws, size_t ws_size,
                              hipStream_t stream) {
    const float* nf_in = (const float*)d_in[0];
    const int*   edges = (const int*)d_in[1];
    const float* W1 = (const float*)d_in[2];
    const float* b1 = (const float*)d_in[3];
    const float* W2 = (const float*)d_in[4];
    const float* b2 = (const float*)d_in[5];
    const float* W3 = (const float*)d_in[6];
    const float* b3 = (const float*)d_in[7];
    const float* Wih = (const float*)d_in[8];
    const float* Whh = (const float*)d_in[9];
    const float* bih = (const float*)d_in[10];
    const float* bhh = (const float*)d_in[11];

    float* nf    = (float*)d_out;
    float* store = (float*)d_ws;
    const size_t nf_bytes    = (size_t)NENV * NNODES * NFEAT * sizeof(float);
    const size_t store_bytes = (size_t)NENV * NNODES * EFEAT * sizeof(float);
    // ws layout: store | W splits | nfh | nfl | cnt | cursor | snode | dnode (~15 MB)
    ushort* W1h = (ushort*)((char*)d_ws + store_bytes);
    ushort* W1l = W1h + 64 * 64;
    ushort* W2h = W1l + 64 * 64;
    ushort* W2l = W2h + 64 * 64;
    ushort* W3h = W2l + 64 * 64;
    ushort* W3l = W3h + 32 * 64;
    ushort* nfh = W3l + 32 * 64;
    ushort* nfl = nfh + (size_t)NENV * NNODES * NPAD;
    int* cnt    = (int*)(nfl + (size_t)NENV * NNODES * NPAD);
    int* cursor = cnt + NNODES;
    int* snode  = cursor + NNODES;
    int* dnode  = snode + E2;

    // --- once per launch: weights, initial split, edge grouping by src ---
    prep_weights<<<1, 256, 0, stream>>>(W1, W2, W3, W1h, W1l, W2h, W2l, W3h, W3l);
    split_nf<<<(NENV * NNODES + 255) / 256, 256, 0, stream>>>(nf_in, nfh, nfl);
    hipMemcpyAsync(nf, nf_in, nf_bytes, hipMemcpyDeviceToDevice, stream);
    hipMemsetAsync(cnt, 0, NNODES * sizeof(int), stream);
    hist_kernel<<<(E2 + 255) / 256, 256, 0, stream>>>(edges, cnt);
    scan_kernel<<<1, 256, 0, stream>>>(cnt, cursor);
    scatter_kernel<<<(E2 + 255) / 256, 256, 0, stream>>>(edges, cursor, snode, dnode);

    const int edge_blocks = (NENV * E2) / ROWS;           // 12500, exact
    dim3 grid_n((NENV * NNODES + 255) / 256);

    for (int it = 0; it < ITERS; it++) {
        hipMemsetAsync(store, 0, store_bytes, stream);
        edge_mlp_mfma<<<edge_blocks, THREADS, 0, stream>>>(nfh, nfl, snode, dnode,
                                                           W1h, W1l, W2h, W2l, W3h, W3l,
                                                           b1, b2, b3, store);
        gru_kernel<<<grid_n, 256, 0, stream>>>(store, Wih, bih, Whh, bhh, nf, nfh, nfl);
    }
}

// Round 12
// 914.913 us; speedup vs baseline: 3.2255x; 1.0366x over previous
//
#include <hip/hip_runtime.h>

#define NFEAT 20
#define EFEAT 20
#define HID   64
#define NENV  16
#define NNODES 5000
#define NEDGES 50000
#define E2 (2*NEDGES)          // 100000 directed edges
#define ITERS 3
#define ROWS 64                // edge rows per block
#define THREADS 128            // 2 waves; wave w owns rows [w*32, w*32+32)
#define NPAD 24                // padded per-node split row (20 + 4 junk) = 3 x 8-chunks

typedef __attribute__((ext_vector_type(8))) short bf16x8;
typedef __attribute__((ext_vector_type(4))) float f32x4;

__device__ __forceinline__ ushort f2b(float f) {   // f32 -> bf16 RNE (prep only)
    unsigned u = __float_as_uint(f);
    u = (u + 0x7fffu + ((u >> 16) & 1u)) >> 16;
    return (ushort)u;
}
__device__ __forceinline__ float b2f(ushort h) {
    return __uint_as_float(((unsigned)h) << 16);
}
// tanh = 1 - 2/(exp(2x)+1); exact limits at +-inf, no clamps. ~5 VALU ops.
__device__ __forceinline__ float fast_tanh(float x) {
    float e = __builtin_exp2f(x * 2.8853900817779268f);   // exp(2x)
    float r = __builtin_amdgcn_rcpf(e + 1.f);
    return fmaf(-2.f, r, 1.f);
}
__device__ __forceinline__ float fast_sigmoid(float x) {
    float e = __builtin_exp2f(x * -1.4426950408889634f);  // exp(-x)
    return __builtin_amdgcn_rcpf(1.f + e);
}

// ---------- edge preprocessing: group directed edges by src (once/launch) ----------
// directed edge e in [0,E2): src = edges[e] (flat), dst = edges[(e+NEDGES) % E2]
__global__ __launch_bounds__(256) void hist_kernel(const int* __restrict__ edges,
                                                   int* __restrict__ cnt) {
    int e = blockIdx.x * 256 + threadIdx.x;
    if (e < E2) atomicAdd(&cnt[edges[e]], 1);
}

__global__ __launch_bounds__(256) void scan_kernel(const int* __restrict__ cnt,
                                                   int* __restrict__ cursor) {
    __shared__ int part[256];
    int t = threadIdx.x;
    int local[20]; int s = 0;
    int base = t * 20;                      // 256*20 = 5120 >= 5000
    #pragma unroll
    for (int i = 0; i < 20; i++) {
        int idx = base + i;
        int v = (idx < NNODES) ? cnt[idx] : 0;
        local[i] = s; s += v;
    }
    part[t] = s;
    __syncthreads();
    for (int d = 1; d < 256; d <<= 1) {     // Hillis-Steele inclusive scan
        int v = (t >= d) ? part[t - d] : 0;
        __syncthreads();
        part[t] += v;
        __syncthreads();
    }
    int excl = part[t] - s;
    #pragma unroll
    for (int i = 0; i < 20; i++) {
        int idx = base + i;
        if (idx < NNODES) cursor[idx] = excl + local[i];
    }
}

// emits src-sorted node-id arrays: snode[pos], dnode[pos] (shared by all envs)
__global__ __launch_bounds__(256) void scatter_kernel(const int* __restrict__ edges,
                                                      int* __restrict__ cursor,
                                                      int* __restrict__ snode,
                                                      int* __restrict__ dnode) {
    int e = blockIdx.x * 256 + threadIdx.x;
    if (e < E2) {
        int s = edges[e];
        int di = e + NEDGES; if (di >= E2) di -= E2;
        int d = edges[di];
        int pos = atomicAdd(&cursor[s], 1);
        snode[pos] = s;
        dnode[pos] = d;
    }
}

// Weights -> split-bf16 (RNE hi + RNE residual), layout [out][k], K padded to 64.
// W1 K-layout matches padded X rows: k<20 = src feats, 24<=k<44 = dst feats, else 0.
__global__ void prep_weights(const float* __restrict__ W1, const float* __restrict__ W2,
                             const float* __restrict__ W3,
                             ushort* __restrict__ W1h, ushort* __restrict__ W1l,
                             ushort* __restrict__ W2h, ushort* __restrict__ W2l,
                             ushort* __restrict__ W3h, ushort* __restrict__ W3l) {
    int t = threadIdx.x;
    for (int i = t; i < 64 * 64; i += 256) {
        int n = i >> 6, k = i & 63;
        float v = 0.f;
        if (k < NFEAT)                          v = W1[n * (2 * NFEAT) + k];
        else if (k >= NPAD && k < NPAD + NFEAT) v = W1[n * (2 * NFEAT) + NFEAT + (k - NPAD)];
        ushort h = f2b(v);
        W1h[i] = h; W1l[i] = f2b(v - b2f(h));
    }
    for (int i = t; i < 64 * 64; i += 256) {
        float v = W2[i];
        ushort h = f2b(v);
        W2h[i] = h; W2l[i] = f2b(v - b2f(h));
    }
    for (int i = t; i < 32 * 64; i += 256) {
        int n = i >> 6, k = i & 63;
        float v = (n < EFEAT) ? W3[n * HID + k] : 0.f;
        ushort h = f2b(v);
        W3h[i] = h; W3l[i] = f2b(v - b2f(h));
    }
}

// Initial per-node truncation split (iteration 0); later iters come from gru_kernel.
__global__ __launch_bounds__(256) void split_nf(const float* __restrict__ nf,
                                                ushort* __restrict__ nfh,
                                                ushort* __restrict__ nfl) {
    int gid = blockIdx.x * 256 + threadIdx.x;
    if (gid >= NENV * NNODES) return;
    const float* p = nf + (size_t)gid * NFEAT;
    ushort* ph = nfh + (size_t)gid * NPAD;
    ushort* pl = nfl + (size_t)gid * NPAD;
    #pragma unroll
    for (int k = 0; k < NFEAT; k++) {
        float v = p[k];
        unsigned u = __float_as_uint(v);
        ph[k] = (ushort)(u >> 16);                      // truncated hi
        float lo = v - __uint_as_float(u & 0xffff0000u);
        pl[k] = (ushort)(__float_as_uint(lo) >> 16);    // truncated lo (~2^-17 repr err)
    }
    *(uint2*)(ph + NFEAT) = make_uint2(0u, 0u);         // zero pad cols 20..23
    *(uint2*)(pl + NFEAT) = make_uint2(0u, 0u);
}

// 64 SORTED edge-rows/block, 2 waves, wave w owns rows [w*32,w*32+32) — all
// LDS traffic wave-local => NO barriers. 16 KB LDS => up to 10 blocks/CU.
// GEMM1: A-fragments loaded DIRECTLY from global split planes (NPAD=24 makes
// every 8-elem fragment chunk a 16B-aligned slice of a node row, or zero).
// GEMM2/3: A from LDS H planes (split, swizzled). Split-bf16 compensated MFMA.
// GEMM3 writes msgs to the wave's own LDS slice; segmented scan -> ~1 atomic
// per (segment,col). No __shfl inside divergent code (keys via LDS col 24).
__global__ __launch_bounds__(THREADS) void edge_mlp_mfma(
    const ushort* __restrict__ nfh, const ushort* __restrict__ nfl,
    const int*   __restrict__ snode, const int* __restrict__ dnode,
    const ushort* __restrict__ W1h, const ushort* __restrict__ W1l,
    const ushort* __restrict__ W2h, const ushort* __restrict__ W2l,
    const ushort* __restrict__ W3h, const ushort* __restrict__ W3l,
    const float* __restrict__ b1, const float* __restrict__ b2,
    const float* __restrict__ b3,
    float* __restrict__ store)
{
    __shared__ bf16x8 smem[1024];                 // 16 KB
    bf16x8* Hhi = smem;                           // 8 KB: h1 -> h2 (hi), swizzled
    bf16x8* Hlo = smem + 512;                     // 8 KB: (lo)
    ushort* Hhi16 = (ushort*)Hhi; ushort* Hlo16 = (ushort*)Hlo;
    float*  msgf  = (float*)smem;                 // GEMM3 overlay, per-wave slice
    int*    msgi  = (int*)smem;                   // int view (keys)

    const int tid  = threadIdx.x;
    const int wave = tid >> 6;
    const int lane = tid & 63;
    const int lr   = lane & 15;      // A-row-in-tile / B-col / C-col
    const int kg   = lane >> 4;      // k-group for A/B; C row-group
    const int m0   = wave * 32;

#define MFMA6(acc, a0h, a0l, a1h, a1l, bh0, bl0, bh1, bl1)                          \
    acc = __builtin_amdgcn_mfma_f32_16x16x32_bf16(a0h, bh0, acc, 0, 0, 0);          \
    acc = __builtin_amdgcn_mfma_f32_16x16x32_bf16(a0l, bh0, acc, 0, 0, 0);          \
    acc = __builtin_amdgcn_mfma_f32_16x16x32_bf16(a0h, bl0, acc, 0, 0, 0);          \
    acc = __builtin_amdgcn_mfma_f32_16x16x32_bf16(a1h, bh1, acc, 0, 0, 0);          \
    acc = __builtin_amdgcn_mfma_f32_16x16x32_bf16(a1l, bh1, acc, 0, 0, 0);          \
    acc = __builtin_amdgcn_mfma_f32_16x16x32_bf16(a1h, bl1, acc, 0, 0, 0);

    // epilogue helper: tanh + truncation split -> H planes (swizzled b16 writes)
#define STORE_H(acc, n_)                                                            \
    {                                                                               \
        int col = (n_) * 16 + lr;                                                   \
        _Pragma("unroll")                                                           \
        for (int r = 0; r < 4; r++) {                                               \
            int row = m0 + m * 16 + kg * 4 + r;                                     \
            float t = fast_tanh(acc[r]);                                            \
            unsigned u = __float_as_uint(t);                                        \
            int idx = row * 64 + (col ^ ((row & 7) << 3));                          \
            Hhi16[idx] = (ushort)(u >> 16);                                         \
            float lo = t - __uint_as_float(u & 0xffff0000u);                        \
            Hlo16[idx] = (ushort)(__float_as_uint(lo) >> 16);                       \
        }                                                                           \
    }

    // ---- GEMM1: X (direct-global, split) @ W1^T +b1, tanh -> H (split, LDS) ----
    {
        bf16x8 wh[4][2], wl[4][2];
        float bb[4];
        #pragma unroll
        for (int n = 0; n < 4; n++) {
            #pragma unroll
            for (int kt = 0; kt < 2; kt++) {
                wh[n][kt] = *(const bf16x8*)(W1h + (n * 16 + lr) * 64 + kt * 32 + kg * 8);
                wl[n][kt] = *(const bf16x8*)(W1l + (n * 16 + lr) * 64 + kt * 32 + kg * 8);
            }
            bb[n] = b1[n * 16 + lr];
        }
        #pragma unroll
        for (int m = 0; m < 2; m++) {
            int rr = m0 + m * 16 + lr;
            int gr = blockIdx.x * ROWS + rr;
            int env = gr / E2;
            int sr  = gr - env * E2;
            int sn  = env * NNODES + snode[sr];
            int dn  = env * NNODES + dnode[sr];
            const ushort* shp = nfh + (size_t)sn * NPAD;
            const ushort* slp = nfl + (size_t)sn * NPAD;
            const ushort* dhp = nfh + (size_t)dn * NPAD;
            const ushort* dlp = nfl + (size_t)dn * NPAD;
            // kt0 chunks: kg<3 -> src chunk kg ; kg==3 -> dst chunk 0
            // kt1 chunks: kg<2 -> dst chunk 1+kg ; else zero
            bf16x8 a0h, a0l, a1h, a1l;
            if (kg < 3) { a0h = *(const bf16x8*)(shp + kg * 8);
                          a0l = *(const bf16x8*)(slp + kg * 8); }
            else        { a0h = *(const bf16x8*)(dhp);
                          a0l = *(const bf16x8*)(dlp); }
            if (kg < 2) { a1h = *(const bf16x8*)(dhp + 8 + kg * 8);
                          a1l = *(const bf16x8*)(dlp + 8 + kg * 8); }
            else        { bf16x8 z = {0,0,0,0,0,0,0,0}; a1h = z; a1l = z; }
            f32x4 acc[4];
            #pragma unroll
            for (int n = 0; n < 4; n++) {
                acc[n] = f32x4{bb[n], bb[n], bb[n], bb[n]};
                MFMA6(acc[n], a0h, a0l, a1h, a1l, wh[n][0], wl[n][0], wh[n][1], wl[n][1])
            }
            #pragma unroll
            for (int n = 0; n < 4; n++) STORE_H(acc[n], n)
        }
    }

    // ---- GEMM2: H1 (LDS, split) @ W2^T +b2, tanh -> H2 (in place) ----
    {
        bf16x8 wh[4][2], wl[4][2];
        float bb[4];
        #pragma unroll
        for (int n = 0; n < 4; n++) {
            #pragma unroll
            for (int kt = 0; kt < 2; kt++) {
                wh[n][kt] = *(const bf16x8*)(W2h + (n * 16 + lr) * 64 + kt * 32 + kg * 8);
                wl[n][kt] = *(const bf16x8*)(W2l + (n * 16 + lr) * 64 + kt * 32 + kg * 8);
            }
            bb[n] = b2[n * 16 + lr];
        }
        #pragma unroll
        for (int m = 0; m < 2; m++) {
            int arow = m0 + m * 16 + lr, sw = arow & 7;
            bf16x8 a0h = Hhi[arow * 8 + (kg ^ sw)];
            bf16x8 a0l = Hlo[arow * 8 + (kg ^ sw)];
            bf16x8 a1h = Hhi[arow * 8 + ((4 + kg) ^ sw)];
            bf16x8 a1l = Hlo[arow * 8 + ((4 + kg) ^ sw)];
            f32x4 acc[4];
            #pragma unroll
            for (int n = 0; n < 4; n++) {
                acc[n] = f32x4{bb[n], bb[n], bb[n], bb[n]};
                MFMA6(acc[n], a0h, a0l, a1h, a1l, wh[n][0], wl[n][0], wh[n][1], wl[n][1])
            }
            #pragma unroll
            for (int n = 0; n < 4; n++) STORE_H(acc[n], n)
        }
    }

    // ---- GEMM3 + segmented reduction ----
    {
        int i_ = lane & 31;
        int gr_i  = blockIdx.x * ROWS + m0 + i_;
        int env_i = gr_i / E2;
        int sr_i  = gr_i - env_i * E2;
        int key   = env_i * NNODES + snode[sr_i];            // full store row id

        bf16x8 wh[2][2], wl[2][2];
        #pragma unroll
        for (int n = 0; n < 2; n++)
            #pragma unroll
            for (int kt = 0; kt < 2; kt++) {
                wh[n][kt] = *(const bf16x8*)(W3h + (n * 16 + lr) * 64 + kt * 32 + kg * 8);
                wl[n][kt] = *(const bf16x8*)(W3l + (n * 16 + lr) * 64 + kt * 32 + kg * 8);
            }
        float bb0 = b3[lr];
        float bb1 = (lr < 4) ? b3[16 + lr] : 0.f;

        // load ALL A fragments first (msg overlay will overwrite this slice)
        f32x4 acc0[2], acc1[2];
        #pragma unroll
        for (int m = 0; m < 2; m++) {
            int arow = m0 + m * 16 + lr, sw = arow & 7;
            bf16x8 a0h = Hhi[arow * 8 + (kg ^ sw)];
            bf16x8 a0l = Hlo[arow * 8 + (kg ^ sw)];
            bf16x8 a1h = Hhi[arow * 8 + ((4 + kg) ^ sw)];
            bf16x8 a1l = Hlo[arow * 8 + ((4 + kg) ^ sw)];
            acc0[m] = f32x4{bb0, bb0, bb0, bb0};
            acc1[m] = f32x4{bb1, bb1, bb1, bb1};
            MFMA6(acc0[m], a0h, a0l, a1h, a1l, wh[0][0], wl[0][0], wh[0][1], wl[0][1])
            MFMA6(acc1[m], a0h, a0l, a1h, a1l, wh[1][0], wl[1][0], wh[1][1], wl[1][1])
        }

        // write f32 msgs into the wave's OWN slice (rows m0..m0+31 consumed)
        // layout: word = wave*1024 + lrow*25 + col; col 24 holds the row key.
        int wbase = wave * 1024;
        #pragma unroll
        for (int m = 0; m < 2; m++) {
            #pragma unroll
            for (int r = 0; r < 4; r++) {
                int lrow = m * 16 + kg * 4 + r;
                msgf[wbase + lrow * 25 + lr] = acc0[m][r];
                if (lr < 4) msgf[wbase + lrow * 25 + 16 + lr] = acc1[m][r];
            }
        }
        if (lane < 32) msgi[wbase + lane * 25 + 24] = key;   // key per row, via LDS

        // segment-boundary flags (FULL exec: shfl/ballot legal here)
        int nxt = __shfl_down(key, 1);
        bool flag = (i_ == 31) || (key != nxt);
        unsigned fm = (unsigned)__ballot(flag);              // bits 0..31 valid

        if (lane < EFEAT) {
            int c = lane;
            float sum = 0.f;
            for (int i = 0; i < 32; i++) {
                sum += msgf[wbase + i * 25 + c];
                if ((fm >> i) & 1u) {
                    int curk = msgi[wbase + i * 25 + 24];    // LDS read, no shfl
                    atomicAdd(store + (size_t)curk * EFEAT + c, sum);
                    sum = 0.f;
                }
            }
        }
    }
#undef STORE_H
#undef MFMA6
}

// GRU single step per (env,node); emits f32 nf AND next iteration's split planes.
__global__ __launch_bounds__(256) void gru_kernel(
    const float* __restrict__ store,
    const float* __restrict__ Wih, const float* __restrict__ bih,
    const float* __restrict__ Whh, const float* __restrict__ bhh,
    float* __restrict__ nf,
    ushort* __restrict__ nfh, ushort* __restrict__ nfl)
{
    int gid = blockIdx.x * blockDim.x + threadIdx.x;
    const int total = NENV * NNODES;
    if (gid >= total) return;

    const float* s = store + (size_t)gid * EFEAT;
    float*       h = nf    + (size_t)gid * NFEAT;
    ushort*     ph = nfh   + (size_t)gid * NPAD;
    ushort*     pl = nfl   + (size_t)gid * NPAD;

    float sv[EFEAT], hv[NFEAT];
    #pragma unroll
    for (int k = 0; k < EFEAT; k++) sv[k] = s[k];
    #pragma unroll
    for (int k = 0; k < NFEAT; k++) hv[k] = h[k];

    for (int t = 0; t < NFEAT; t++) {
        float ir = bih[t],            hr = bhh[t];
        float iz = bih[NFEAT + t],    hz = bhh[NFEAT + t];
        float in_ = bih[2*NFEAT + t], hn = bhh[2*NFEAT + t];
        const float* wr = Wih + t * EFEAT;
        const float* wz = Wih + (NFEAT + t) * EFEAT;
        const float* wn = Wih + (2*NFEAT + t) * EFEAT;
        #pragma unroll
        for (int k = 0; k < EFEAT; k++) {
            ir  = fmaf(sv[k], wr[k], ir);
            iz  = fmaf(sv[k], wz[k], iz);
            in_ = fmaf(sv[k], wn[k], in_);
        }
        const float* vr = Whh + t * NFEAT;
        const float* vz = Whh + (NFEAT + t) * NFEAT;
        const float* vn = Whh + (2*NFEAT + t) * NFEAT;
        #pragma unroll
        for (int k = 0; k < NFEAT; k++) {
            hr = fmaf(hv[k], vr[k], hr);
            hz = fmaf(hv[k], vz[k], hz);
            hn = fmaf(hv[k], vn[k], hn);
        }
        float r = fast_sigmoid(ir + hr);
        float z = fast_sigmoid(iz + hz);
        float n = fast_tanh(in_ + r * hn);
        float hw = (1.f - z) * n + z * hv[t];
        h[t] = hw;
        unsigned u = __float_as_uint(hw);
        ph[t] = (ushort)(u >> 16);
        float lo = hw - __uint_as_float(u & 0xffff0000u);
        pl[t] = (ushort)(__float_as_uint(lo) >> 16);
    }
    *(uint2*)(ph + NFEAT) = make_uint2(0u, 0u);
    *(uint2*)(pl + NFEAT) = make_uint2(0u, 0u);
}

extern "C" void kernel_launch(void* const* d_in, const int* in_sizes, int n_in,
                              void* d_out, int out_size, void* d_ws, size_t ws_size,
                              hipStream_t stream) {
    const float* nf_in = (const float*)d_in[0];
    const int*   edges = (const int*)d_in[1];
    const float* W1 = (const float*)d_in[2];
    const float* b1 = (const float*)d_in[3];
    const float* W2 = (const float*)d_in[4];
    const float* b2 = (const float*)d_in[5];
    const float* W3 = (const float*)d_in[6];
    const float* b3 = (const float*)d_in[7];
    const float* Wih = (const float*)d_in[8];
    const float* Whh = (const float*)d_in[9];
    const float* bih = (const float*)d_in[10];
    const float* bhh = (const float*)d_in[11];

    float* nf    = (float*)d_out;
    float* store = (float*)d_ws;
    const size_t nf_bytes    = (size_t)NENV * NNODES * NFEAT * sizeof(float);
    const size_t store_bytes = (size_t)NENV * NNODES * EFEAT * sizeof(float);
    // ws layout: store | W splits | nfh | nfl | cnt | cursor | snode | dnode (~15 MB)
    ushort* W1h = (ushort*)((char*)d_ws + store_bytes);
    ushort* W1l = W1h + 64 * 64;
    ushort* W2h = W1l + 64 * 64;
    ushort* W2l = W2h + 64 * 64;
    ushort* W3h = W2l + 64 * 64;
    ushort* W3l = W3h + 32 * 64;
    ushort* nfh = W3l + 32 * 64;
    ushort* nfl = nfh + (size_t)NENV * NNODES * NPAD;
    int* cnt    = (int*)(nfl + (size_t)NENV * NNODES * NPAD);
    int* cursor = cnt + NNODES;
    int* snode  = cursor + NNODES;
    int* dnode  = snode + E2;

    // --- once per launch: weights, initial split, edge grouping by src ---
    prep_weights<<<1, 256, 0, stream>>>(W1, W2, W3, W1h, W1l, W2h, W2l, W3h, W3l);
    split_nf<<<(NENV * NNODES + 255) / 256, 256, 0, stream>>>(nf_in, nfh, nfl);
    hipMemcpyAsync(nf, nf_in, nf_bytes, hipMemcpyDeviceToDevice, stream);
    hipMemsetAsync(cnt, 0, NNODES * sizeof(int), stream);
    hist_kernel<<<(E2 + 255) / 256, 256, 0, stream>>>(edges, cnt);
    scan_kernel<<<1, 256, 0, stream>>>(cnt, cursor);
    scatter_kernel<<<(E2 + 255) / 256, 256, 0, stream>>>(edges, cursor, snode, dnode);

    const int edge_blocks = (NENV * E2) / ROWS;           // 25000, exact
    dim3 grid_n((NENV * NNODES + 255) / 256);

    for (int it = 0; it < ITERS; it++) {
        hipMemsetAsync(store, 0, store_bytes, stream);
        edge_mlp_mfma<<<edge_blocks, THREADS, 0, stream>>>(nfh, nfl, snode, dnode,
                                                           W1h, W1l, W2h, W2l, W3h, W3l,
                                                           b1, b2, b3, store);
        gru_kernel<<<grid_n, 256, 0, stream>>>(store, Wih, bih, Whh, bhh, nf, nfh, nfl);
    }
}

// Round 13
// 565.348 us; speedup vs baseline: 5.2199x; 1.6183x over previous
//
#include <hip/hip_runtime.h>

#define NFEAT 20
#define EFEAT 20
#define HID   64
#define NENV  16
#define NNODES 5000
#define NEDGES 50000
#define E2 (2*NEDGES)          // 100000 directed edges
#define ITERS 3
#define ROWS 64                // edge rows per block
#define THREADS 128            // 2 waves; wave w owns rows [w*32, w*32+32)
#define NPAD 24                // padded per-node fp16 row (20 + 4 junk) = 3 x 8-chunks

typedef __attribute__((ext_vector_type(8))) _Float16 f16x8;
typedef __attribute__((ext_vector_type(4))) float f32x4;

__device__ __forceinline__ ushort f2h(float f) {   // f32 -> fp16 RNE
    _Float16 h = (_Float16)f;
    return *(ushort*)&h;
}
// tanh = 1 - 2/(exp(2x)+1); exact limits at +-inf, no clamps. ~5 VALU ops.
__device__ __forceinline__ float fast_tanh(float x) {
    float e = __builtin_exp2f(x * 2.8853900817779268f);   // exp(2x)
    float r = __builtin_amdgcn_rcpf(e + 1.f);
    return fmaf(-2.f, r, 1.f);
}
__device__ __forceinline__ float fast_sigmoid(float x) {
    float e = __builtin_exp2f(x * -1.4426950408889634f);  // exp(-x)
    return __builtin_amdgcn_rcpf(1.f + e);
}

// ---------- edge preprocessing: group directed edges by src (once/launch) ----------
__global__ __launch_bounds__(256) void hist_kernel(const int* __restrict__ edges,
                                                   int* __restrict__ cnt) {
    int e = blockIdx.x * 256 + threadIdx.x;
    if (e < E2) atomicAdd(&cnt[edges[e]], 1);
}

__global__ __launch_bounds__(256) void scan_kernel(const int* __restrict__ cnt,
                                                   int* __restrict__ cursor) {
    __shared__ int part[256];
    int t = threadIdx.x;
    int local[20]; int s = 0;
    int base = t * 20;                      // 256*20 = 5120 >= 5000
    #pragma unroll
    for (int i = 0; i < 20; i++) {
        int idx = base + i;
        int v = (idx < NNODES) ? cnt[idx] : 0;
        local[i] = s; s += v;
    }
    part[t] = s;
    __syncthreads();
    for (int d = 1; d < 256; d <<= 1) {     // Hillis-Steele inclusive scan
        int v = (t >= d) ? part[t - d] : 0;
        __syncthreads();
        part[t] += v;
        __syncthreads();
    }
    int excl = part[t] - s;
    #pragma unroll
    for (int i = 0; i < 20; i++) {
        int idx = base + i;
        if (idx < NNODES) cursor[idx] = excl + local[i];
    }
}

// emits src-sorted node-id arrays: snode[pos], dnode[pos] (shared by all envs)
__global__ __launch_bounds__(256) void scatter_kernel(const int* __restrict__ edges,
                                                      int* __restrict__ cursor,
                                                      int* __restrict__ snode,
                                                      int* __restrict__ dnode) {
    int e = blockIdx.x * 256 + threadIdx.x;
    if (e < E2) {
        int s = edges[e];
        int di = e + NEDGES; if (di >= E2) di -= E2;
        int d = edges[di];
        int pos = atomicAdd(&cursor[s], 1);
        snode[pos] = s;
        dnode[pos] = d;
    }
}

// Weights -> fp16, layout [out][k], K padded to 64.
// W1 K-layout matches padded X rows: k<20 = src feats, 24<=k<44 = dst feats, else 0.
__global__ void prep_weights(const float* __restrict__ W1, const float* __restrict__ W2,
                             const float* __restrict__ W3,
                             ushort* __restrict__ W1p, ushort* __restrict__ W2p,
                             ushort* __restrict__ W3p) {
    int t = threadIdx.x;
    for (int i = t; i < 64 * 64; i += 256) {
        int n = i >> 6, k = i & 63;
        float v = 0.f;
        if (k < NFEAT)                          v = W1[n * (2 * NFEAT) + k];
        else if (k >= NPAD && k < NPAD + NFEAT) v = W1[n * (2 * NFEAT) + NFEAT + (k - NPAD)];
        W1p[i] = f2h(v);
    }
    for (int i = t; i < 64 * 64; i += 256)
        W2p[i] = f2h(W2[i]);
    for (int i = t; i < 32 * 64; i += 256) {
        int n = i >> 6, k = i & 63;
        W3p[i] = (n < EFEAT) ? f2h(W3[n * HID + k]) : (ushort)0;
    }
}

// Initial per-node fp16 conversion (iteration 0); later iters from gru_kernel.
__global__ __launch_bounds__(256) void conv_nf(const float* __restrict__ nf,
                                               ushort* __restrict__ nfp) {
    int gid = blockIdx.x * 256 + threadIdx.x;
    if (gid >= NENV * NNODES) return;
    const float* p = nf + (size_t)gid * NFEAT;
    ushort* ph = nfp + (size_t)gid * NPAD;
    #pragma unroll
    for (int k = 0; k < NFEAT; k++) ph[k] = f2h(p[k]);
    *(uint2*)(ph + NFEAT) = make_uint2(0u, 0u);         // zero pad cols 20..23
}

// 64 SORTED edge-rows/block, 2 waves, wave w owns rows [w*32,w*32+32) — all
// LDS traffic wave-local => NO barriers. 8 KB LDS (single fp16 H plane).
// fp16 MFMA (f32 accum): one MFMA per K-tile — 1/3 the MFMA of split-bf16,
// justified by round-4 calibration: all-bf16 err 0.139, fp16 is 8x tighter.
// GEMM1: A-fragments DIRECT from global fp16 plane (NPAD=24 -> 16B chunks).
// GEMM2/3: A from LDS H plane (swizzled). GEMM3 -> per-wave LDS msg slice ->
// segmented scan -> ~1 atomicAdd per (segment,col). Keys via LDS col 24.
__global__ __launch_bounds__(THREADS) void edge_mlp_mfma(
    const ushort* __restrict__ nfp,
    const int*   __restrict__ snode, const int* __restrict__ dnode,
    const ushort* __restrict__ W1p, const ushort* __restrict__ W2p,
    const ushort* __restrict__ W3p,
    const float* __restrict__ b1, const float* __restrict__ b2,
    const float* __restrict__ b3,
    float* __restrict__ store)
{
    __shared__ ushort smem16[4096];               // 8 KB
    ushort* Hp = smem16;                          // H plane: [64 rows][64 cols] fp16, swizzled
    float*  msgf = (float*)smem16;                // GEMM3 overlay, per-wave slice
    int*    msgi = (int*)smem16;                  // int view (keys)

    const int tid  = threadIdx.x;
    const int wave = tid >> 6;
    const int lane = tid & 63;
    const int lr   = lane & 15;      // A-row-in-tile / B-col / C-col
    const int kg   = lane >> 4;      // k-group for A/B; C row-group
    const int m0   = wave * 32;

#define MFMA2(acc, a0, a1, b0, b1)                                                  \
    acc = __builtin_amdgcn_mfma_f32_16x16x32_f16(a0, b0, acc, 0, 0, 0);             \
    acc = __builtin_amdgcn_mfma_f32_16x16x32_f16(a1, b1, acc, 0, 0, 0);

    // epilogue helper: tanh -> fp16 -> H plane (swizzled b16 writes)
#define STORE_H(acc, n_)                                                            \
    {                                                                               \
        int col = (n_) * 16 + lr;                                                   \
        _Pragma("unroll")                                                           \
        for (int r = 0; r < 4; r++) {                                               \
            int row = m0 + m * 16 + kg * 4 + r;                                     \
            int idx = row * 64 + (col ^ ((row & 7) << 3));                          \
            Hp[idx] = f2h(fast_tanh(acc[r]));                                       \
        }                                                                           \
    }

    // ---- GEMM1: X (direct-global fp16) @ W1^T +b1, tanh -> H (LDS) ----
    {
        f16x8 wp[4][2];
        float bb[4];
        #pragma unroll
        for (int n = 0; n < 4; n++) {
            #pragma unroll
            for (int kt = 0; kt < 2; kt++)
                wp[n][kt] = *(const f16x8*)(W1p + (n * 16 + lr) * 64 + kt * 32 + kg * 8);
            bb[n] = b1[n * 16 + lr];
        }
        #pragma unroll
        for (int m = 0; m < 2; m++) {
            int rr = m0 + m * 16 + lr;
            int gr = blockIdx.x * ROWS + rr;
            int env = gr / E2;
            int sr  = gr - env * E2;
            const ushort* sp_ = nfp + (size_t)(env * NNODES + snode[sr]) * NPAD;
            const ushort* dp_ = nfp + (size_t)(env * NNODES + dnode[sr]) * NPAD;
            // kt0 chunks: kg<3 -> src chunk kg ; kg==3 -> dst chunk 0
            // kt1 chunks: kg<2 -> dst chunk 1+kg ; else zero
            f16x8 a0, a1;
            if (kg < 3) a0 = *(const f16x8*)(sp_ + kg * 8);
            else        a0 = *(const f16x8*)(dp_);
            if (kg < 2) a1 = *(const f16x8*)(dp_ + 8 + kg * 8);
            else        a1 = f16x8{(_Float16)0,(_Float16)0,(_Float16)0,(_Float16)0,
                                   (_Float16)0,(_Float16)0,(_Float16)0,(_Float16)0};
            f32x4 acc[4];
            #pragma unroll
            for (int n = 0; n < 4; n++) {
                acc[n] = f32x4{bb[n], bb[n], bb[n], bb[n]};
                MFMA2(acc[n], a0, a1, wp[n][0], wp[n][1])
            }
            #pragma unroll
            for (int n = 0; n < 4; n++) STORE_H(acc[n], n)
        }
    }

    // ---- GEMM2: H1 (LDS) @ W2^T +b2, tanh -> H2 (in place) ----
    {
        f16x8 wp[4][2];
        float bb[4];
        #pragma unroll
        for (int n = 0; n < 4; n++) {
            #pragma unroll
            for (int kt = 0; kt < 2; kt++)
                wp[n][kt] = *(const f16x8*)(W2p + (n * 16 + lr) * 64 + kt * 32 + kg * 8);
            bb[n] = b2[n * 16 + lr];
        }
        #pragma unroll
        for (int m = 0; m < 2; m++) {
            int arow = m0 + m * 16 + lr, sw = arow & 7;
            f16x8 a0 = *(const f16x8*)(Hp + arow * 64 + ((kg ^ sw) << 3));
            f16x8 a1 = *(const f16x8*)(Hp + arow * 64 + (((4 + kg) ^ sw) << 3));
            f32x4 acc[4];
            #pragma unroll
            for (int n = 0; n < 4; n++) {
                acc[n] = f32x4{bb[n], bb[n], bb[n], bb[n]};
                MFMA2(acc[n], a0, a1, wp[n][0], wp[n][1])
            }
            #pragma unroll
            for (int n = 0; n < 4; n++) STORE_H(acc[n], n)
        }
    }

    // ---- GEMM3 + segmented reduction ----
    {
        int i_ = lane & 31;
        int gr_i  = blockIdx.x * ROWS + m0 + i_;
        int env_i = gr_i / E2;
        int sr_i  = gr_i - env_i * E2;
        int key   = env_i * NNODES + snode[sr_i];            // full store row id

        f16x8 wp[2][2];
        #pragma unroll
        for (int n = 0; n < 2; n++)
            #pragma unroll
            for (int kt = 0; kt < 2; kt++)
                wp[n][kt] = *(const f16x8*)(W3p + (n * 16 + lr) * 64 + kt * 32 + kg * 8);
        float bb0 = b3[lr];
        float bb1 = (lr < 4) ? b3[16 + lr] : 0.f;

        // load ALL A fragments first (msg overlay will overwrite this slice)
        f32x4 acc0[2], acc1[2];
        #pragma unroll
        for (int m = 0; m < 2; m++) {
            int arow = m0 + m * 16 + lr, sw = arow & 7;
            f16x8 a0 = *(const f16x8*)(Hp + arow * 64 + ((kg ^ sw) << 3));
            f16x8 a1 = *(const f16x8*)(Hp + arow * 64 + (((4 + kg) ^ sw) << 3));
            acc0[m] = f32x4{bb0, bb0, bb0, bb0};
            acc1[m] = f32x4{bb1, bb1, bb1, bb1};
            MFMA2(acc0[m], a0, a1, wp[0][0], wp[0][1])
            MFMA2(acc1[m], a0, a1, wp[1][0], wp[1][1])
        }

        // write f32 msgs into the wave's OWN slice (rows m0..m0+31 consumed)
        // layout: word = wave*1024 + lrow*25 + col; col 24 holds the row key.
        int wbase = wave * 1024;
        #pragma unroll
        for (int m = 0; m < 2; m++) {
            #pragma unroll
            for (int r = 0; r < 4; r++) {
                int lrow = m * 16 + kg * 4 + r;
                msgf[wbase + lrow * 25 + lr] = acc0[m][r];
                if (lr < 4) msgf[wbase + lrow * 25 + 16 + lr] = acc1[m][r];
            }
        }
        if (lane < 32) msgi[wbase + lane * 25 + 24] = key;   // key per row, via LDS

        // segment-boundary flags (FULL exec: shfl/ballot legal here)
        int nxt = __shfl_down(key, 1);
        bool flag = (i_ == 31) || (key != nxt);
        unsigned fm = (unsigned)__ballot(flag);              // bits 0..31 valid

        if (lane < EFEAT) {
            int c = lane;
            float sum = 0.f;
            for (int i = 0; i < 32; i++) {
                sum += msgf[wbase + i * 25 + c];
                if ((fm >> i) & 1u) {
                    int curk = msgi[wbase + i * 25 + 24];    // LDS read, no shfl
                    atomicAdd(store + (size_t)curk * EFEAT + c, sum);
                    sum = 0.f;
                }
            }
        }
    }
#undef STORE_H
#undef MFMA2
}

// GRU single step per (env,node); emits f32 nf AND next iteration's fp16 row.
__global__ __launch_bounds__(256) void gru_kernel(
    const float* __restrict__ store,
    const float* __restrict__ Wih, const float* __restrict__ bih,
    const float* __restrict__ Whh, const float* __restrict__ bhh,
    float* __restrict__ nf,
    ushort* __restrict__ nfp)
{
    int gid = blockIdx.x * blockDim.x + threadIdx.x;
    const int total = NENV * NNODES;
    if (gid >= total) return;

    const float* s = store + (size_t)gid * EFEAT;
    float*       h = nf    + (size_t)gid * NFEAT;
    ushort*     ph = nfp   + (size_t)gid * NPAD;

    float sv[EFEAT], hv[NFEAT];
    #pragma unroll
    for (int k = 0; k < EFEAT; k++) sv[k] = s[k];
    #pragma unroll
    for (int k = 0; k < NFEAT; k++) hv[k] = h[k];

    for (int t = 0; t < NFEAT; t++) {
        float ir = bih[t],            hr = bhh[t];
        float iz = bih[NFEAT + t],    hz = bhh[NFEAT + t];
        float in_ = bih[2*NFEAT + t], hn = bhh[2*NFEAT + t];
        const float* wr = Wih + t * EFEAT;
        const float* wz = Wih + (NFEAT + t) * EFEAT;
        const float* wn = Wih + (2*NFEAT + t) * EFEAT;
        #pragma unroll
        for (int k = 0; k < EFEAT; k++) {
            ir  = fmaf(sv[k], wr[k], ir);
            iz  = fmaf(sv[k], wz[k], iz);
            in_ = fmaf(sv[k], wn[k], in_);
        }
        const float* vr = Whh + t * NFEAT;
        const float* vz = Whh + (NFEAT + t) * NFEAT;
        const float* vn = Whh + (2*NFEAT + t) * NFEAT;
        #pragma unroll
        for (int k = 0; k < NFEAT; k++) {
            hr = fmaf(hv[k], vr[k], hr);
            hz = fmaf(hv[k], vz[k], hz);
            hn = fmaf(hv[k], vn[k], hn);
        }
        float r = fast_sigmoid(ir + hr);
        float z = fast_sigmoid(iz + hz);
        float n = fast_tanh(in_ + r * hn);
        float hw = (1.f - z) * n + z * hv[t];
        h[t] = hw;
        ph[t] = f2h(hw);
    }
    *(uint2*)(ph + NFEAT) = make_uint2(0u, 0u);
}

extern "C" void kernel_launch(void* const* d_in, const int* in_sizes, int n_in,
                              void* d_out, int out_size, void* d_ws, size_t ws_size,
                              hipStream_t stream) {
    const float* nf_in = (const float*)d_in[0];
    const int*   edges = (const int*)d_in[1];
    const float* W1 = (const float*)d_in[2];
    const float* b1 = (const float*)d_in[3];
    const float* W2 = (const float*)d_in[4];
    const float* b2 = (const float*)d_in[5];
    const float* W3 = (const float*)d_in[6];
    const float* b3 = (const float*)d_in[7];
    const float* Wih = (const float*)d_in[8];
    const float* Whh = (const float*)d_in[9];
    const float* bih = (const float*)d_in[10];
    const float* bhh = (const float*)d_in[11];

    float* nf    = (float*)d_out;
    float* store = (float*)d_ws;
    const size_t nf_bytes    = (size_t)NENV * NNODES * NFEAT * sizeof(float);
    const size_t store_bytes = (size_t)NENV * NNODES * EFEAT * sizeof(float);
    // ws layout: store | W fp16 | nfp | cnt | cursor | snode | dnode  (~11 MB)
    ushort* W1p = (ushort*)((char*)d_ws + store_bytes);
    ushort* W2p = W1p + 64 * 64;
    ushort* W3p = W2p + 64 * 64;
    ushort* nfp = W3p + 32 * 64;
    int* cnt    = (int*)(nfp + (size_t)NENV * NNODES * NPAD);
    int* cursor = cnt + NNODES;
    int* snode  = cursor + NNODES;
    int* dnode  = snode + E2;

    // --- once per launch: weights, initial conversion, edge grouping by src ---
    prep_weights<<<1, 256, 0, stream>>>(W1, W2, W3, W1p, W2p, W3p);
    conv_nf<<<(NENV * NNODES + 255) / 256, 256, 0, stream>>>(nf_in, nfp);
    hipMemcpyAsync(nf, nf_in, nf_bytes, hipMemcpyDeviceToDevice, stream);
    hipMemsetAsync(cnt, 0, NNODES * sizeof(int), stream);
    hist_kernel<<<(E2 + 255) / 256, 256, 0, stream>>>(edges, cnt);
    scan_kernel<<<1, 256, 0, stream>>>(cnt, cursor);
    scatter_kernel<<<(E2 + 255) / 256, 256, 0, stream>>>(edges, cursor, snode, dnode);

    const int edge_blocks = (NENV * E2) / ROWS;           // 25000, exact
    dim3 grid_n((NENV * NNODES + 255) / 256);

    for (int it = 0; it < ITERS; it++) {
        hipMemsetAsync(store, 0, store_bytes, stream);
        edge_mlp_mfma<<<edge_blocks, THREADS, 0, stream>>>(nfp, snode, dnode,
                                                           W1p, W2p, W3p,
                                                           b1, b2, b3, store);
        gru_kernel<<<grid_n, 256, 0, stream>>>(store, Wih, bih, Whh, bhh, nf, nfp);
    }
}